// Round 1
// baseline (29626.630 us; speedup 1.0000x reference)
//
#include <hip/hip_runtime.h>
#include <hip/hip_bf16.h>
#include <math.h>

typedef __hip_bfloat16 bf16;

// ---------- helpers ----------
static __device__ __forceinline__ float bf2f(unsigned short u) {
  return __uint_as_float(((unsigned int)u) << 16);
}
static __device__ __forceinline__ unsigned short f2bf_bits(float f) {
  unsigned int x = __float_as_uint(f);
  unsigned int lsb = (x >> 16) & 1u;
  x += 0x7fffu + lsb;           // round-to-nearest-even
  return (unsigned short)(x >> 16);
}

struct F4 { float a, b, c, d; };

template <typename T> struct VecIn;
template <> struct VecIn<float> {
  static __device__ __forceinline__ F4 ld(const float* p) {
    float4 v = *reinterpret_cast<const float4*>(p);
    return {v.x, v.y, v.z, v.w};
  }
  static __device__ __forceinline__ float ld1(const float* p) { return *p; }
};
template <> struct VecIn<bf16> {
  static __device__ __forceinline__ F4 ld(const bf16* p) {
    uint2 u = *reinterpret_cast<const uint2*>(p);
    return {bf2f((unsigned short)(u.x & 0xffffu)), bf2f((unsigned short)(u.x >> 16)),
            bf2f((unsigned short)(u.y & 0xffffu)), bf2f((unsigned short)(u.y >> 16))};
  }
  static __device__ __forceinline__ float ld1(const bf16* p) {
    return bf2f(*reinterpret_cast<const unsigned short*>(p));
  }
};

template <typename T> static __device__ __forceinline__ void stor(T* p, float v);
template <> __device__ __forceinline__ void stor<float>(float* p, float v) { *p = v; }
template <> __device__ __forceinline__ void stor<bf16>(bf16* p, float v) {
  *reinterpret_cast<unsigned short*>(p) = f2bf_bits(v);
}

// ---------- weight transform: OIHW f32 -> [ky][kx][ic][oc] (f32 or bf16) ----------
template <typename TD>
__global__ __launch_bounds__(256) void wxform_knl(const float* __restrict__ src,
                                                  TD* __restrict__ dst,
                                                  int OC, int IC, int KH, int KW) {
  int total = OC * IC * KH * KW;
  int i = blockIdx.x * 256 + threadIdx.x;
  if (i >= total) return;
  int kx = i % KW; int t = i / KW;
  int ky = t % KH; t /= KH;
  int ic = t % IC; int oc = t / IC;
  stor(dst + ((size_t)(ky * KW + kx) * IC + ic) * OC + oc, src[i]);
}

// ---------- NCHW f32 -> NHWC f32 ----------
__global__ __launch_bounds__(256) void nchw2nhwc_knl(const float* __restrict__ src,
                                                     float* __restrict__ dst,
                                                     int N, int C, int H, int W) {
  int total = N * C * H * W;
  int i = blockIdx.x * 256 + threadIdx.x;
  if (i >= total) return;
  int x = i % W; int t = i / W;
  int y = t % H; t /= H;
  int c = t % C; int n = t / C;
  dst[(((size_t)n * H + y) * W + x) * C + c] = src[i];
}

// ---------- generic direct conv, NHWC, weights [ky][kx][ic][oc] ----------
// block = 256 threads: 4 waves; wave w -> 8 pixels, lanes -> 64 consecutive oc.
template <typename TI, typename TW, typename TO, bool SILU>
__global__ __launch_bounds__(256) void conv_knl(
    const TI* __restrict__ in, const TW* __restrict__ w, const float* __restrict__ bias,
    TO* __restrict__ out, int N, int IH, int IW, int IC,
    int OH, int OW, int OC, int stride, int pad, int KH, int KW) {
  const int lane = threadIdx.x & 63;
  const int wid  = threadIdx.x >> 6;
  const int oc   = blockIdx.y * 64 + lane;
  const int M    = N * OH * OW;
  const int pixBase = blockIdx.x * 32 + wid * 8;

  float bv = bias[oc];
  float acc[8];
#pragma unroll
  for (int p = 0; p < 8; ++p) acc[p] = bv;

  int oyv[8], oxv[8], nv[8];
  bool pv[8];
#pragma unroll
  for (int p = 0; p < 8; ++p) {
    int pix = pixBase + p;
    pv[p] = pix < M;
    int pp = pv[p] ? pix : 0;
    oxv[p] = pp % OW; int t = pp / OW;
    oyv[p] = t % OH;  nv[p] = t / OH;
  }

  for (int ky = 0; ky < KH; ++ky) {
    int iyv[8]; bool vy[8];
#pragma unroll
    for (int p = 0; p < 8; ++p) {
      iyv[p] = oyv[p] * stride - pad + ky;
      vy[p] = pv[p] && (iyv[p] >= 0) && (iyv[p] < IH);
    }
    for (int kx = 0; kx < KW; ++kx) {
      const TW* wp = w + (size_t)(ky * KW + kx) * IC * OC + oc;
      int ib[8]; bool v[8];
#pragma unroll
      for (int p = 0; p < 8; ++p) {
        int ix = oxv[p] * stride - pad + kx;
        v[p] = vy[p] && (ix >= 0) && (ix < IW);
        ib[p] = ((nv[p] * IH + iyv[p]) * IW + ix) * IC;
      }
      int ic = 0;
      for (; ic + 4 <= IC; ic += 4) {
        float w0 = VecIn<TW>::ld1(wp + (size_t)(ic + 0) * OC);
        float w1 = VecIn<TW>::ld1(wp + (size_t)(ic + 1) * OC);
        float w2 = VecIn<TW>::ld1(wp + (size_t)(ic + 2) * OC);
        float w3 = VecIn<TW>::ld1(wp + (size_t)(ic + 3) * OC);
#pragma unroll
        for (int p = 0; p < 8; ++p) {
          if (v[p]) {
            F4 i4 = VecIn<TI>::ld(in + ib[p] + ic);
            acc[p] = fmaf(i4.a, w0, acc[p]);
            acc[p] = fmaf(i4.b, w1, acc[p]);
            acc[p] = fmaf(i4.c, w2, acc[p]);
            acc[p] = fmaf(i4.d, w3, acc[p]);
          }
        }
      }
      for (; ic < IC; ++ic) {
        float w0 = VecIn<TW>::ld1(wp + (size_t)ic * OC);
#pragma unroll
        for (int p = 0; p < 8; ++p)
          if (v[p]) acc[p] = fmaf(VecIn<TI>::ld1(in + ib[p] + ic), w0, acc[p]);
      }
    }
  }
#pragma unroll
  for (int p = 0; p < 8; ++p) {
    if (pv[p]) {
      float r = acc[p];
      if (SILU) r = r / (1.0f + __expf(-r));
      stor(out + (size_t)(pixBase + p) * OC + oc, r);
    }
  }
}

// ---------- bilinear 2x upsample (align_corners=False), NHWC bf16 ----------
__global__ __launch_bounds__(256) void up2_knl(const bf16* __restrict__ in,
                                               bf16* __restrict__ out,
                                               int N, int H, int W, int C) {
  int C4 = C >> 2;
  int OW = 2 * W, OH = 2 * H;
  size_t total = (size_t)N * OH * OW * C4;
  size_t tid = (size_t)blockIdx.x * 256 + threadIdx.x;
  if (tid >= total) return;
  int c4 = (int)(tid % C4); size_t t = tid / C4;
  int ox = (int)(t % OW); t /= OW;
  int oy = (int)(t % OH); int n = (int)(t / OH);
  float sy = 0.5f * oy - 0.25f;
  float sx = 0.5f * ox - 0.25f;
  int y0 = (int)floorf(sy); float fy = sy - (float)y0;
  int x0 = (int)floorf(sx); float fx = sx - (float)x0;
  int y0c = y0 < 0 ? 0 : y0; int y1c = (y0 + 1 > H - 1) ? (H - 1) : (y0 + 1);
  int x0c = x0 < 0 ? 0 : x0; int x1c = (x0 + 1 > W - 1) ? (W - 1) : (x0 + 1);
  const bf16* base = in + (size_t)n * H * W * C + c4 * 4;
  F4 t00 = VecIn<bf16>::ld(base + ((size_t)y0c * W + x0c) * C);
  F4 t01 = VecIn<bf16>::ld(base + ((size_t)y0c * W + x1c) * C);
  F4 t10 = VecIn<bf16>::ld(base + ((size_t)y1c * W + x0c) * C);
  F4 t11 = VecIn<bf16>::ld(base + ((size_t)y1c * W + x1c) * C);
  float w00 = (1.f - fy) * (1.f - fx), w01 = (1.f - fy) * fx;
  float w10 = fy * (1.f - fx),         w11 = fy * fx;
  float r0 = w00 * t00.a + w01 * t01.a + w10 * t10.a + w11 * t11.a;
  float r1 = w00 * t00.b + w01 * t01.b + w10 * t10.b + w11 * t11.b;
  float r2 = w00 * t00.c + w01 * t01.c + w10 * t10.c + w11 * t11.c;
  float r3 = w00 * t00.d + w01 * t01.d + w10 * t10.d + w11 * t11.d;
  union { unsigned short us[4]; uint2 u; } pk;
  pk.us[0] = f2bf_bits(r0); pk.us[1] = f2bf_bits(r1);
  pk.us[2] = f2bf_bits(r2); pk.us[3] = f2bf_bits(r3);
  *reinterpret_cast<uint2*>(out + (((size_t)n * OH + oy) * OW + ox) * C + c4 * 4) = pk.u;
}

// ---------- VQ: per-row argmin over K codes (D=64), writes q (bf16) + loss (f32) ----------
__global__ __launch_bounds__(256) void vq_knl(const float* __restrict__ zq,
                                              const float* __restrict__ embT,  // [64][K]
                                              const float* __restrict__ emb,   // [K][64]
                                              bf16* __restrict__ q,
                                              float* __restrict__ loss, int K) {
  __shared__ float z[64];
  __shared__ float sd[256];
  __shared__ int   si[256];
  int row = blockIdx.x;
  int tid = threadIdx.x;
  if (tid < 64) z[tid] = zq[(size_t)row * 64 + tid];
  __syncthreads();
  float best = 3.4e38f; int bi = 0;
  for (int k = tid; k < K; k += 256) {
    float d2 = 0.f;
#pragma unroll
    for (int d = 0; d < 64; ++d) {
      float diff = embT[d * K + k] - z[d];
      d2 = fmaf(diff, diff, d2);
    }
    if (d2 < best) { best = d2; bi = k; }
  }
  sd[tid] = best; si[tid] = bi;
  __syncthreads();
  for (int s = 128; s > 0; s >>= 1) {
    if (tid < s) {
      float od = sd[tid + s]; int oi = si[tid + s];
      if (od < sd[tid] || (od == sd[tid] && oi < si[tid])) { sd[tid] = od; si[tid] = oi; }
    }
    __syncthreads();
  }
  int idx = si[0];
  if (tid < 64) {
    float e  = emb[(size_t)idx * 64 + tid];
    float zv = z[tid];
    float diff = e - zv;
    stor(q + (size_t)row * 64 + tid, e);
    loss[(size_t)row * 64 + tid] = 1.25f * diff * diff;
  }
}

// ---------- final 3x3 conv (64->3) + sigmoid, NHWC in -> NCHW f32 out ----------
__global__ __launch_bounds__(256) void conv_out_sig(const bf16* __restrict__ in,
                                                    const float* __restrict__ w,  // [tap][64][3]
                                                    const float* __restrict__ bias,
                                                    float* __restrict__ out,
                                                    int N, int H, int W) {
  __shared__ float ws[1728];
  for (int i = threadIdx.x; i < 1728; i += 256) ws[i] = w[i];
  __syncthreads();
  int tid = blockIdx.x * 256 + threadIdx.x;
  int total = N * 3 * H * W;
  if (tid >= total) return;
  int x = tid % W; int t = tid / W;
  int y = t % H; t /= H;
  int c = t % 3; int n = t / 3;
  float acc = bias[c];
  for (int ky = 0; ky < 3; ++ky) {
    int iy = y - 1 + ky;
    if (iy < 0 || iy >= H) continue;
    for (int kx = 0; kx < 3; ++kx) {
      int ix = x - 1 + kx;
      if (ix < 0 || ix >= W) continue;
      const bf16* ip = in + (((size_t)n * H + iy) * W + ix) * 64;
      const float* wp = ws + (ky * 3 + kx) * 192 + c;
#pragma unroll
      for (int ic = 0; ic < 64; ic += 4) {
        F4 i4 = VecIn<bf16>::ld(ip + ic);
        acc = fmaf(i4.a, wp[(ic + 0) * 3], acc);
        acc = fmaf(i4.b, wp[(ic + 1) * 3], acc);
        acc = fmaf(i4.c, wp[(ic + 2) * 3], acc);
        acc = fmaf(i4.d, wp[(ic + 3) * 3], acc);
      }
    }
  }
  out[tid] = 1.0f / (1.0f + expf(-acc));
}

// ---------- host ----------
extern "C" void kernel_launch(void* const* d_in, const int* in_sizes, int n_in,
                              void* d_out, int out_size, void* d_ws, size_t ws_size,
                              hipStream_t stream) {
  (void)in_sizes; (void)n_in; (void)out_size; (void)ws_size;
  const float* x    = (const float*)d_in[0];
  const float* ew1  = (const float*)d_in[1];  const float* eb1 = (const float*)d_in[2];
  const float* ew2  = (const float*)d_in[3];  const float* eb2 = (const float*)d_in[4];
  const float* ew3  = (const float*)d_in[5];  const float* eb3 = (const float*)d_in[6];
  const float* ew4  = (const float*)d_in[7];  const float* eb4 = (const float*)d_in[8];
  const float* pqw  = (const float*)d_in[9];  const float* pqb = (const float*)d_in[10];
  const float* emb  = (const float*)d_in[11];
  const float* poqw = (const float*)d_in[12]; const float* poqb = (const float*)d_in[13];
  const float* dw1  = (const float*)d_in[14]; const float* db1 = (const float*)d_in[15];
  const float* dw2  = (const float*)d_in[16]; const float* db2 = (const float*)d_in[17];
  const float* dw3  = (const float*)d_in[18]; const float* db3 = (const float*)d_in[19];
  const float* dw4  = (const float*)d_in[20]; const float* db4 = (const float*)d_in[21];
  const float* oww  = (const float*)d_in[22]; const float* ob  = (const float*)d_in[23];

  char* wsb = (char*)d_ws;
  size_t off = 0;
  auto alloc = [&](size_t bytes) -> char* {
    char* p = wsb + off;
    off += (bytes + 255) & ~(size_t)255;
    return p;
  };

  float* w_e1  = (float*)alloc(1728u * 4);
  float* w_e2  = (float*)alloc(73728u * 4);
  float* w_e3  = (float*)alloc(294912u * 4);
  float* w_e4  = (float*)alloc(1179648u * 4);
  float* w_pq  = (float*)alloc(32768u * 4);
  float* w_embT= (float*)alloc(65536u * 4);
  bf16*  w_poq = (bf16*)alloc(32768u * 2);
  bf16*  w_d1  = (bf16*)alloc(2359296u * 2);
  bf16*  w_d2  = (bf16*)alloc(1179648u * 2);
  bf16*  w_d3  = (bf16*)alloc(294912u * 2);
  bf16*  w_d4  = (bf16*)alloc(73728u * 2);
  float* w_ow  = (float*)alloc(1728u * 4);
  char* R0 = alloc(67108864ull + 4096);   // max 67.1 MB tenants
  char* R1 = alloc(134217728ull + 4096);  // max 134.2 MB tenants

  auto gsz = [](size_t n) { return dim3((unsigned)((n + 255) / 256)); };

  // weight transforms (cheap; every launch => deterministic)
  wxform_knl<float><<<gsz(1728), 256, 0, stream>>>(ew1, w_e1, 64, 3, 3, 3);
  wxform_knl<float><<<gsz(73728), 256, 0, stream>>>(ew2, w_e2, 128, 64, 3, 3);
  wxform_knl<float><<<gsz(294912), 256, 0, stream>>>(ew3, w_e3, 256, 128, 3, 3);
  wxform_knl<float><<<gsz(1179648), 256, 0, stream>>>(ew4, w_e4, 512, 256, 3, 3);
  wxform_knl<float><<<gsz(32768), 256, 0, stream>>>(pqw, w_pq, 64, 512, 1, 1);
  wxform_knl<float><<<gsz(65536), 256, 0, stream>>>(emb, w_embT, 1024, 64, 1, 1);  // emb^T [64][1024]
  wxform_knl<bf16><<<gsz(32768), 256, 0, stream>>>(poqw, w_poq, 512, 64, 1, 1);
  wxform_knl<bf16><<<gsz(2359296), 256, 0, stream>>>(dw1, w_d1, 512, 512, 3, 3);
  wxform_knl<bf16><<<gsz(1179648), 256, 0, stream>>>(dw2, w_d2, 256, 512, 3, 3);
  wxform_knl<bf16><<<gsz(294912), 256, 0, stream>>>(dw3, w_d3, 128, 256, 3, 3);
  wxform_knl<bf16><<<gsz(73728), 256, 0, stream>>>(dw4, w_d4, 64, 128, 3, 3);
  wxform_knl<float><<<gsz(1728), 256, 0, stream>>>(oww, w_ow, 3, 64, 3, 3);

  // activation ping-pong
  float* xh  = (float*)R0;
  float* a1  = (float*)R1;
  float* a2  = (float*)R0;
  float* a3  = (float*)R1;
  float* a4  = (float*)R0;
  float* zq  = (float*)R1;
  bf16*  qb  = (bf16*)R0;
  bf16*  poq = (bf16*)R1;
  bf16*  c1  = (bf16*)R0;
  bf16*  u1  = (bf16*)R1;
  bf16*  c2  = (bf16*)R0;
  bf16*  u2  = (bf16*)R1;
  bf16*  c3  = (bf16*)R0;
  bf16*  u3  = (bf16*)R1;
  bf16*  c4  = (bf16*)R0;
  float* out0 = (float*)d_out;
  float* loss = out0 + 1572864;

  nchw2nhwc_knl<<<gsz(1572864), 256, 0, stream>>>(x, xh, 8, 3, 256, 256);

  // encoder (f32)
  conv_knl<float, float, float, true ><<<dim3(16384, 1), 256, 0, stream>>>(xh, w_e1, eb1, a1, 8, 256, 256, 3, 256, 256, 64, 1, 1, 3, 3);
  conv_knl<float, float, float, true ><<<dim3(4096, 2),  256, 0, stream>>>(a1, w_e2, eb2, a2, 8, 256, 256, 64, 128, 128, 128, 2, 1, 3, 3);
  conv_knl<float, float, float, true ><<<dim3(1024, 4),  256, 0, stream>>>(a2, w_e3, eb3, a3, 8, 128, 128, 128, 64, 64, 256, 2, 1, 3, 3);
  conv_knl<float, float, float, false><<<dim3(256, 8),   256, 0, stream>>>(a3, w_e4, eb4, a4, 8, 64, 64, 256, 32, 32, 512, 2, 1, 3, 3);
  conv_knl<float, float, float, false><<<dim3(256, 1),   256, 0, stream>>>(a4, w_pq, pqb, zq, 8, 32, 32, 512, 32, 32, 64, 1, 0, 1, 1);

  // VQ
  vq_knl<<<8192, 256, 0, stream>>>(zq, w_embT, emb, qb, loss, 1024);

  // decoder (bf16)
  conv_knl<bf16, bf16, bf16, false><<<dim3(256, 8),   256, 0, stream>>>(qb,  w_poq, poqb, poq, 8, 32, 32, 64, 32, 32, 512, 1, 0, 1, 1);
  conv_knl<bf16, bf16, bf16, true ><<<dim3(256, 8),   256, 0, stream>>>(poq, w_d1, db1, c1, 8, 32, 32, 512, 32, 32, 512, 1, 1, 3, 3);
  up2_knl<<<gsz(8ull * 64 * 64 * 128), 256, 0, stream>>>(c1, u1, 8, 32, 32, 512);
  conv_knl<bf16, bf16, bf16, true ><<<dim3(1024, 4),  256, 0, stream>>>(u1, w_d2, db2, c2, 8, 64, 64, 512, 64, 64, 256, 1, 1, 3, 3);
  up2_knl<<<gsz(8ull * 128 * 128 * 64), 256, 0, stream>>>(c2, u2, 8, 64, 64, 256);
  conv_knl<bf16, bf16, bf16, true ><<<dim3(4096, 2),  256, 0, stream>>>(u2, w_d3, db3, c3, 8, 128, 128, 256, 128, 128, 128, 1, 1, 3, 3);
  up2_knl<<<gsz(8ull * 256 * 256 * 32), 256, 0, stream>>>(c3, u3, 8, 128, 128, 128);
  conv_knl<bf16, bf16, bf16, false><<<dim3(16384, 1), 256, 0, stream>>>(u3, w_d4, db4, c4, 8, 256, 256, 128, 256, 256, 64, 1, 1, 3, 3);

  // final conv + sigmoid -> NCHW f32
  conv_out_sig<<<gsz(1572864), 256, 0, stream>>>(c4, w_ow, ob, out0, 8, 256, 256);
}

// Round 3
// 1774.253 us; speedup vs baseline: 16.6981x; 16.6981x over previous
//
#include <hip/hip_runtime.h>
#include <hip/hip_bf16.h>
#include <math.h>

typedef __hip_bfloat16 bf16;
typedef __attribute__((ext_vector_type(8))) short short8;
typedef __attribute__((ext_vector_type(4))) float f32x4;

// ---------- scalar helpers ----------
static __device__ __forceinline__ float bf2f(unsigned short u) {
  return __uint_as_float(((unsigned int)u) << 16);
}
static __device__ __forceinline__ unsigned short f2bf_bits(float f) {
  unsigned int x = __float_as_uint(f);
  x += 0x7fffu + ((x >> 16) & 1u);  // RNE
  return (unsigned short)(x >> 16);
}
static __device__ __forceinline__ void sto_bf(bf16* p, float v) {
  *reinterpret_cast<unsigned short*>(p) = f2bf_bits(v);
}
struct F4 { float a, b, c, d; };
static __device__ __forceinline__ F4 ld4bf(const bf16* p) {
  uint2 u = *reinterpret_cast<const uint2*>(p);
  return { bf2f((unsigned short)(u.x & 0xffffu)), bf2f((unsigned short)(u.x >> 16)),
           bf2f((unsigned short)(u.y & 0xffffu)), bf2f((unsigned short)(u.y >> 16)) };
}

// async global->LDS, 16B per lane
static __device__ __forceinline__ void g2l16(const void* g, void* l) {
  __builtin_amdgcn_global_load_lds(
      (const __attribute__((address_space(1))) unsigned int*)g,
      (__attribute__((address_space(3))) unsigned int*)l, 16, 0, 0);
}

// ---------- weight transforms ----------
// OIHW f32 -> [tap][oc][ic] bf16 hi (+ optional lo residual)
__global__ __launch_bounds__(256) void wx_toc(const float* __restrict__ src,
                                              bf16* __restrict__ hi, bf16* __restrict__ lo,
                                              int OC, int IC, int T) {
  int total = T * OC * IC;
  int i = blockIdx.x * 256 + threadIdx.x;
  if (i >= total) return;
  int tap = i / (OC * IC); int r = i - tap * OC * IC;
  int oc = r / IC; int ic = r - oc * IC;
  float v = src[(oc * IC + ic) * T + tap];
  float h = bf2f(f2bf_bits(v));
  sto_bf(hi + i, h);
  if (lo) sto_bf(lo + i, v - h);
}
// OIHW f32 -> [tap][ic][oc] f32 (for direct-conv kernels)
__global__ __launch_bounds__(256) void wx_tico(const float* __restrict__ src,
                                               float* __restrict__ dst,
                                               int OC, int IC, int T) {
  int total = T * OC * IC;
  int i = blockIdx.x * 256 + threadIdx.x;
  if (i >= total) return;
  int tap = i / (IC * OC); int r = i - tap * IC * OC;
  int ic = r / OC; int oc = r - ic * OC;
  dst[i] = src[(oc * IC + ic) * T + tap];
}
// emb [1024][64] -> embT [64][1024]
__global__ __launch_bounds__(256) void wx_embT(const float* __restrict__ src, float* __restrict__ dst) {
  int i = blockIdx.x * 256 + threadIdx.x;
  if (i >= 65536) return;
  int d = i >> 10, k = i & 1023;
  dst[i] = src[k * 64 + d];
}

// ---------- zero the 1-px border of a padded NHWC bf16 tensor ----------
__global__ __launch_bounds__(256) void bzero_knl(bf16* __restrict__ buf, int N, int Hp, int Wp, int C) {
  long per = 2 * Wp + 2 * Hp - 4;
  long total = (long)N * per * C;
  long t = (long)blockIdx.x * 256 + threadIdx.x;
  if (t >= total) return;
  int c = (int)(t % C); long q = t / C;
  int pos = (int)(q % per); int n = (int)(q / per);
  int y, x;
  if (pos < Wp) { y = 0; x = pos; }
  else if (pos < 2 * Wp) { y = Hp - 1; x = pos - Wp; }
  else { int r = pos - 2 * Wp; y = 1 + (r >> 1); x = (r & 1) ? Wp - 1 : 0; }
  *reinterpret_cast<unsigned short*>(&buf[(((long)n * Hp + y) * Wp + x) * C + c]) = 0;
}

// ---------- MFMA implicit-GEMM conv ----------
// NHWC input (padded by 1 when TAP9), weights [tap][oc][ic] bf16.
// Block: 256 thr = 4 waves; tile BM x 64(oc), BK=64.
//   BM=128 (plain): waves stacked in M, each 32x64 (MREP2 x NREP4).
//   BM=64 (split hi/lo input+weights, 3-MFMA compensation): waves 2x2, each 32x32.
// LDS tiles XOR-swizzled (T2) via pre-swizzled GLOBAL source (rule #21),
// linear global_load_lds destinations.
// omode: 0 = f32 plain [p][OC]; 1 = bf16 (opt padded); 2 = bf16 hi/lo split (padded).
template <bool SPLIT, int BM, bool TAP9>
__global__ __launch_bounds__(256) void conv_mfma(
    const bf16* __restrict__ inhi, const bf16* __restrict__ inlo,
    int IHp, int IWp, int IC, int kcLog, int stride,
    const bf16* __restrict__ whi, const bf16* __restrict__ wlo,
    const float* __restrict__ bias, int OC, int OH, int OW,
    int omode, int opad, int OHp, int OWp, int silu,
    void* __restrict__ outp, bf16* __restrict__ outlo)
{
  constexpr int NB = SPLIT ? 2 : 1;
  constexpr int AIW = BM / 32;        // A stage instrs per wave
  constexpr int MREP = 2;
  constexpr int NREP = (BM == 128) ? 4 : 2;
  __shared__ uint4 ldsA[2][NB][BM * 8];
  __shared__ uint4 ldsB[2][NB][64 * 8];

  const int tid = threadIdx.x;
  const int lane = tid & 63;
  const int wv = tid >> 6;
  const int pixBase = blockIdx.x * BM;
  const int ocBase = blockIdx.y * 64;
  const int OHW = OH * OW;

  int aoff[AIW], asl[AIW];
#pragma unroll
  for (int j = 0; j < AIW; ++j) {
    int I = wv * AIW + j;
    int m = I * 8 + (lane >> 3);
    int icoff = ((lane & 7) ^ (m & 7)) * 8;   // swizzled source chunk
    int p = pixBase + m;
    int n = p / OHW; int r = p - n * OHW;
    int oy = r / OW; int ox = r - oy * OW;
    aoff[j] = ((n * IHp + oy * stride) * IWp + ox * stride) * IC + icoff;
    asl[j] = I * 64 + lane;
  }
  int boff[2], bsl[2];
#pragma unroll
  for (int j = 0; j < 2; ++j) {
    int I = wv * 2 + j;
    int ocr = I * 8 + (lane >> 3);
    int icoff = ((lane & 7) ^ (ocr & 7)) * 8;
    boff[j] = (ocBase + ocr) * IC + icoff;
    bsl[j] = I * 64 + lane;
  }

  const int kcMask = (1 << kcLog) - 1;
  const int steps = (TAP9 ? 9 : 1) << kcLog;

  auto stage = [&](int buf, int s) {
    int tap = s >> kcLog;
    int k0 = (s & kcMask) << 6;
    int ta = 0;
    if (TAP9) { int ky = tap / 3, kx = tap - ky * 3; ta = (ky * IWp + kx) * IC; }
    int ga = ta + k0;
#pragma unroll
    for (int j = 0; j < AIW; ++j) {
      g2l16(inhi + aoff[j] + ga, &ldsA[buf][0][asl[j]]);
      if constexpr (SPLIT) g2l16(inlo + aoff[j] + ga, &ldsA[buf][1][asl[j]]);
    }
    int gb = tap * OC * IC + k0;
#pragma unroll
    for (int j = 0; j < 2; ++j) {
      g2l16(whi + boff[j] + gb, &ldsB[buf][0][bsl[j]]);
      if constexpr (SPLIT) g2l16(wlo + boff[j] + gb, &ldsB[buf][1][bsl[j]]);
    }
  };

  const int wrow = (BM == 128) ? wv * 32 : (wv >> 1) * 32;
  const int wcol = (BM == 128) ? 0 : (wv & 1) * 32;

  f32x4 acc[MREP][NREP];
#pragma unroll
  for (int i = 0; i < MREP; ++i)
#pragma unroll
    for (int j = 0; j < NREP; ++j) { acc[i][j][0] = 0.f; acc[i][j][1] = 0.f; acc[i][j][2] = 0.f; acc[i][j][3] = 0.f; }

  stage(0, 0);
  __syncthreads();
  int cur = 0;
  for (int s = 0; s < steps; ++s) {
    if (s + 1 < steps) stage(cur ^ 1, s + 1);   // prefetch next tile (overlaps compute)
#pragma unroll
    for (int kk = 0; kk < 2; ++kk) {
      int kb = kk * 4 + (lane >> 4);
      short8 af[NB][MREP], bfr[NB][NREP];
#pragma unroll
      for (int mr = 0; mr < MREP; ++mr) {
        int row = wrow + mr * 16 + (lane & 15);
        int slot = row * 8 + (kb ^ (row & 7));
        af[0][mr] = *(const short8*)&ldsA[cur][0][slot];
        if constexpr (SPLIT) af[1][mr] = *(const short8*)&ldsA[cur][1][slot];
      }
#pragma unroll
      for (int nr = 0; nr < NREP; ++nr) {
        int ocr = wcol + nr * 16 + (lane & 15);
        int slot = ocr * 8 + (kb ^ (ocr & 7));
        bfr[0][nr] = *(const short8*)&ldsB[cur][0][slot];
        if constexpr (SPLIT) bfr[1][nr] = *(const short8*)&ldsB[cur][1][slot];
      }
#pragma unroll
      for (int mr = 0; mr < MREP; ++mr)
#pragma unroll
        for (int nr = 0; nr < NREP; ++nr) {
          acc[mr][nr] = __builtin_amdgcn_mfma_f32_16x16x32_bf16(af[0][mr], bfr[0][nr], acc[mr][nr], 0, 0, 0);
          if constexpr (SPLIT) {
            acc[mr][nr] = __builtin_amdgcn_mfma_f32_16x16x32_bf16(af[1][mr], bfr[0][nr], acc[mr][nr], 0, 0, 0);
            acc[mr][nr] = __builtin_amdgcn_mfma_f32_16x16x32_bf16(af[0][mr], bfr[1][nr], acc[mr][nr], 0, 0, 0);
          }
        }
    }
    __syncthreads();
    cur ^= 1;
  }

  // epilogue: C/D layout col=lane&15, row=(lane>>4)*4+reg (m89-verified)
#pragma unroll
  for (int mr = 0; mr < MREP; ++mr) {
#pragma unroll
    for (int nr = 0; nr < NREP; ++nr) {
      int col = ocBase + wcol + nr * 16 + (lane & 15);
      float bv = bias[col];
#pragma unroll
      for (int r = 0; r < 4; ++r) {
        int row = wrow + mr * 16 + (lane >> 4) * 4 + r;
        float v = acc[mr][nr][r] + bv;
        if (silu) v = v / (1.f + expf(-v));
        int p = pixBase + row;
        if (omode == 0) {
          ((float*)outp)[p * OC + col] = v;
        } else {
          int n = p / OHW; int rr = p - n * OHW;
          int oy = rr / OW; int ox = rr - oy * OW;
          int ob = ((n * OHp + oy + opad) * OWp + ox + opad) * OC + col;
          float h = bf2f(f2bf_bits(v));
          sto_bf((bf16*)outp + ob, h);
          if (omode == 2) sto_bf(outlo + ob, v - h);
        }
      }
    }
  }
}

// ---------- e1: 3->64 3x3 direct f32, silu, split hi/lo to padded NHWC (4 images) ----------
__global__ __launch_bounds__(256) void e1_knl(const float* __restrict__ x,
                                              const float* __restrict__ w,  // [tap][3][64]
                                              const float* __restrict__ bias,
                                              bf16* __restrict__ ahi, bf16* __restrict__ alo) {
  long t = (long)blockIdx.x * 256 + threadIdx.x;  // 4*256*256*64
  int oc = (int)(t & 63); long p = t >> 6;
  int ox = (int)(p & 255); int oy = (int)((p >> 8) & 255); int n = (int)(p >> 16);
  float acc = bias[oc];
#pragma unroll
  for (int ky = 0; ky < 3; ++ky) {
    int iy = oy - 1 + ky;
    if ((unsigned)iy < 256u) {
#pragma unroll
      for (int kx = 0; kx < 3; ++kx) {
        int ix = ox - 1 + kx;
        if ((unsigned)ix < 256u) {
          int base = ((n * 3) * 256 + iy) * 256 + ix;
          const float* wp = w + (ky * 3 + kx) * 192 + oc;
          acc = fmaf(x[base], wp[0], acc);
          acc = fmaf(x[base + 65536], wp[64], acc);
          acc = fmaf(x[base + 131072], wp[128], acc);
        }
      }
    }
  }
  float v = acc / (1.f + expf(-acc));
  long ob = (((long)n * 258 + oy + 1) * 258 + ox + 1) * 64 + oc;
  float h = bf2f(f2bf_bits(v));
  sto_bf(ahi + ob, h);
  sto_bf(alo + ob, v - h);
}

// ---------- bilinear 2x upsample, unpadded in -> padded out interior ----------
__global__ __launch_bounds__(256) void up2_knl(const bf16* __restrict__ in, bf16* __restrict__ out,
                                               int N, int H, int W, int C) {
  int C4 = C >> 2;
  int OW = 2 * W, OH = 2 * H;
  long total = (long)N * OH * OW * C4;
  long tid = (long)blockIdx.x * 256 + threadIdx.x;
  if (tid >= total) return;
  int c4 = (int)(tid % C4); long t = tid / C4;
  int ox = (int)(t % OW); t /= OW;
  int oy = (int)(t % OH); int n = (int)(t / OH);
  float sy = 0.5f * oy - 0.25f, sx = 0.5f * ox - 0.25f;
  int y0 = (int)floorf(sy); float fy = sy - (float)y0;
  int x0 = (int)floorf(sx); float fx = sx - (float)x0;
  int y0c = y0 < 0 ? 0 : y0; int y1c = (y0 + 1 > H - 1) ? (H - 1) : (y0 + 1);
  int x0c = x0 < 0 ? 0 : x0; int x1c = (x0 + 1 > W - 1) ? (W - 1) : (x0 + 1);
  const bf16* base = in + (long)n * H * W * C + c4 * 4;
  F4 t00 = ld4bf(base + ((long)y0c * W + x0c) * C);
  F4 t01 = ld4bf(base + ((long)y0c * W + x1c) * C);
  F4 t10 = ld4bf(base + ((long)y1c * W + x0c) * C);
  F4 t11 = ld4bf(base + ((long)y1c * W + x1c) * C);
  float w00 = (1.f - fy) * (1.f - fx), w01 = (1.f - fy) * fx;
  float w10 = fy * (1.f - fx), w11 = fy * fx;
  union { unsigned short us[4]; uint2 u; } pk;
  pk.us[0] = f2bf_bits(w00 * t00.a + w01 * t01.a + w10 * t10.a + w11 * t11.a);
  pk.us[1] = f2bf_bits(w00 * t00.b + w01 * t01.b + w10 * t10.b + w11 * t11.b);
  pk.us[2] = f2bf_bits(w00 * t00.c + w01 * t01.c + w10 * t10.c + w11 * t11.c);
  pk.us[3] = f2bf_bits(w00 * t00.d + w01 * t01.d + w10 * t10.d + w11 * t11.d);
  *reinterpret_cast<uint2*>(out + (((long)n * (OH + 2) + oy + 1) * (OW + 2) + ox + 1) * C + c4 * 4) = pk.u;
}

// ---------- VQ: per-row argmin over 1024 codes, D=64 ----------
__global__ __launch_bounds__(256) void vq_knl(const float* __restrict__ zq,
                                              const float* __restrict__ embT,  // [64][1024]
                                              const float* __restrict__ emb,   // [1024][64]
                                              bf16* __restrict__ q,
                                              float* __restrict__ loss, int K) {
  __shared__ float z[64];
  __shared__ float sd[256];
  __shared__ int si[256];
  int row = blockIdx.x;
  int tid = threadIdx.x;
  if (tid < 64) z[tid] = zq[(long)row * 64 + tid];
  __syncthreads();
  float best = 3.4e38f; int bi = 0;
  for (int k = tid; k < K; k += 256) {
    float d2 = 0.f;
#pragma unroll
    for (int d = 0; d < 64; ++d) {
      float diff = embT[d * K + k] - z[d];
      d2 = fmaf(diff, diff, d2);
    }
    if (d2 < best) { best = d2; bi = k; }
  }
  sd[tid] = best; si[tid] = bi;
  __syncthreads();
  for (int s = 128; s > 0; s >>= 1) {
    if (tid < s) {
      float od = sd[tid + s]; int oi = si[tid + s];
      if (od < sd[tid] || (od == sd[tid] && oi < si[tid])) { sd[tid] = od; si[tid] = oi; }
    }
    __syncthreads();
  }
  int idx = si[0];
  if (tid < 64) {
    float e = emb[(long)idx * 64 + tid];
    float diff = e - z[tid];
    sto_bf(q + (long)row * 64 + tid, e);
    loss[(long)row * 64 + tid] = 1.25f * diff * diff;
  }
}

// ---------- final 3x3 conv (64->3) + sigmoid, padded NHWC in -> NCHW f32 (4 images) ----------
__global__ __launch_bounds__(256) void outc_knl(const bf16* __restrict__ in,   // [4][258][258][64]
                                                const float* __restrict__ w,   // [tap][64][3]
                                                const float* __restrict__ bias,
                                                float* __restrict__ out) {     // [4][3][256][256]
  __shared__ float ws[1728];
  for (int i = threadIdx.x; i < 1728; i += 256) ws[i] = w[i];
  __syncthreads();
  int tid = blockIdx.x * 256 + threadIdx.x;  // 786432 exactly
  int x = tid & 255; int t = tid >> 8;
  int y = t & 255; t >>= 8;
  int c = t % 3; int n = t / 3;
  float acc = bias[c];
  for (int ky = 0; ky < 3; ++ky) {
    for (int kx = 0; kx < 3; ++kx) {
      const bf16* ip = in + (((long)(n * 258) + (y + ky)) * 258 + (x + kx)) * 64;
      const float* wp = ws + (ky * 3 + kx) * 192 + c;
#pragma unroll
      for (int ic = 0; ic < 64; ic += 4) {
        F4 i4 = ld4bf(ip + ic);
        acc = fmaf(i4.a, wp[(ic + 0) * 3], acc);
        acc = fmaf(i4.b, wp[(ic + 1) * 3], acc);
        acc = fmaf(i4.c, wp[(ic + 2) * 3], acc);
        acc = fmaf(i4.d, wp[(ic + 3) * 3], acc);
      }
    }
  }
  out[tid] = 1.f / (1.f + expf(-acc));
}

// ---------- host ----------
extern "C" void kernel_launch(void* const* d_in, const int* in_sizes, int n_in,
                              void* d_out, int out_size, void* d_ws, size_t ws_size,
                              hipStream_t stream) {
  (void)in_sizes; (void)n_in; (void)out_size; (void)ws_size;
  const float* x    = (const float*)d_in[0];
  const float* ew1  = (const float*)d_in[1];  const float* eb1 = (const float*)d_in[2];
  const float* ew2  = (const float*)d_in[3];  const float* eb2 = (const float*)d_in[4];
  const float* ew3  = (const float*)d_in[5];  const float* eb3 = (const float*)d_in[6];
  const float* ew4  = (const float*)d_in[7];  const float* eb4 = (const float*)d_in[8];
  const float* pqw  = (const float*)d_in[9];  const float* pqb = (const float*)d_in[10];
  const float* emb  = (const float*)d_in[11];
  const float* poqw = (const float*)d_in[12]; const float* poqb = (const float*)d_in[13];
  const float* dw1  = (const float*)d_in[14]; const float* db1 = (const float*)d_in[15];
  const float* dw2  = (const float*)d_in[16]; const float* db2 = (const float*)d_in[17];
  const float* dw3  = (const float*)d_in[18]; const float* db3 = (const float*)d_in[19];
  const float* dw4  = (const float*)d_in[20]; const float* db4 = (const float*)d_in[21];
  const float* oww  = (const float*)d_in[22]; const float* ob  = (const float*)d_in[23];

  char* wsb = (char*)d_ws;
  size_t off = 0;
  auto alloc = [&](size_t b) -> char* {
    char* p = wsb + off;
    off = (off + b + 255) & ~(size_t)255;
    return p;
  };

  float* w_e1   = (float*)alloc(1728 * 4);
  float* w_ow   = (float*)alloc(1728 * 4);
  float* w_embT = (float*)alloc(65536 * 4);
  bf16* w_e2h = (bf16*)alloc(73728 * 2);   bf16* w_e2l = (bf16*)alloc(73728 * 2);
  bf16* w_e3h = (bf16*)alloc(294912 * 2);  bf16* w_e3l = (bf16*)alloc(294912 * 2);
  bf16* w_e4h = (bf16*)alloc(1179648 * 2); bf16* w_e4l = (bf16*)alloc(1179648 * 2);
  bf16* w_pqh = (bf16*)alloc(32768 * 2);   bf16* w_pql = (bf16*)alloc(32768 * 2);
  bf16* w_poq = (bf16*)alloc(32768 * 2);
  bf16* w_d1  = (bf16*)alloc(2359296 * 2);
  bf16* w_d2  = (bf16*)alloc(1179648 * 2);
  bf16* w_d3  = (bf16*)alloc(294912 * 2);
  bf16* w_d4  = (bf16*)alloc(73728 * 2);

  char* RA = alloc(68161536);   // [a1h|a1l] (enc half) -> u3h (dec half)
  char* RB = alloc(68161536);   // enc-half overlay -> decoder arena
  char* RC = alloc(28360704);   // qb | poqO | u1h

  // --- encoder-half overlays in RA/RB ---
  bf16* a1h = (bf16*)RA;                       // 4*258*258*64*2 = 34,080,768
  bf16* a1l = (bf16*)(RA + 34080768);
  bf16* u3h_ = (bf16*)RA;                      // 4*258*258*128*2 = 68,161,536 (decoder)

  bf16* a2h = (bf16*)RB;                       // 4*130*130*128*2 = 17,305,600
  bf16* a2l = (bf16*)(RB + 17305600);
  bf16* a3h = (bf16*)(RB + 34611200);          // 4*66*66*256*2 = 8,921,088
  bf16* a3l = (bf16*)(RB + 43532288);
  bf16* a4h = (bf16*)(RB + 52453376);          // 4*32*32*512*2 = 4,194,304
  bf16* a4l = (bf16*)(RB + 56647680);
  float* zqH = (float*)(RB + 60841984);        // 4096*64*4 = 1,048,576

  // --- decoder overlay in RB (per half) ---
  bf16* u2h_ = (bf16*)RB;                      // 4*130*130*256*2 = 34,611,200
  bf16* c4h_ = (bf16*)RB;                      // 4*258*258*64*2 = 34,080,768
  bf16* c3h_ = (bf16*)(RB + 34611200);         // 4*128*128*128*2 = 16,777,216
  bf16* c2h_ = (bf16*)(RB + 51388416);         // 4*64*64*256*2 = 8,388,608
  bf16* c1h_ = (bf16*)(RB + 59777024);         // 4*32*32*512*2 = 4,194,304

  // --- RC overlays ---
  bf16* qb   = (bf16*)RC;                      // 8192*64*2 = 1,048,576 (full batch)
  bf16* poqO = (bf16*)(RC + 1048576);          // 8*34*34*512*2 = 9,469,952
  bf16* u1h_ = (bf16*)(RC + 10518528);         // 4*66*66*512*2 = 17,842,176

  float* out0 = (float*)d_out;
  float* loss = out0 + 1572864;

  auto G1 = [](long n) { return dim3((unsigned)((n + 255) / 256)); };

  // weight transforms
  wx_tico<<<G1(1728), 256, 0, stream>>>(ew1, w_e1, 64, 3, 9);
  wx_tico<<<G1(1728), 256, 0, stream>>>(oww, w_ow, 3, 64, 9);
  wx_embT<<<G1(65536), 256, 0, stream>>>(emb, w_embT);
  wx_toc<<<G1(73728), 256, 0, stream>>>(ew2, w_e2h, w_e2l, 128, 64, 9);
  wx_toc<<<G1(294912), 256, 0, stream>>>(ew3, w_e3h, w_e3l, 256, 128, 9);
  wx_toc<<<G1(1179648), 256, 0, stream>>>(ew4, w_e4h, w_e4l, 512, 256, 9);
  wx_toc<<<G1(32768), 256, 0, stream>>>(pqw, w_pqh, w_pql, 64, 512, 1);
  wx_toc<<<G1(32768), 256, 0, stream>>>(poqw, w_poq, (bf16*)nullptr, 512, 64, 1);
  wx_toc<<<G1(2359296), 256, 0, stream>>>(dw1, w_d1, (bf16*)nullptr, 512, 512, 9);
  wx_toc<<<G1(1179648), 256, 0, stream>>>(dw2, w_d2, (bf16*)nullptr, 256, 512, 9);
  wx_toc<<<G1(294912), 256, 0, stream>>>(dw3, w_d3, (bf16*)nullptr, 128, 256, 9);
  wx_toc<<<G1(73728), 256, 0, stream>>>(dw4, w_d4, (bf16*)nullptr, 64, 128, 9);

  auto bz = [&](bf16* p, int N, int Hp, int Wp, int C) {
    long tot = (long)N * (2 * Wp + 2 * Hp - 4) * C;
    bzero_knl<<<G1(tot), 256, 0, stream>>>(p, N, Hp, Wp, C);
  };
  // borders for encoder-half buffers (interiors fully rewritten each half)
  bz(a1h, 4, 258, 258, 64); bz(a1l, 4, 258, 258, 64);
  bz(a2h, 4, 130, 130, 128); bz(a2l, 4, 130, 130, 128);
  bz(a3h, 4, 66, 66, 256);   bz(a3l, 4, 66, 66, 256);

  // ---------- encoder + VQ, two batch-halves ----------
  for (int h = 0; h < 2; ++h) {
    const float* xh = x + (size_t)h * 786432;  // 4 images NCHW
    e1_knl<<<65536, 256, 0, stream>>>(xh, w_e1, eb1, a1h, a1l);
    conv_mfma<true, 64, true><<<dim3(1024, 2), 256, 0, stream>>>(
        a1h, a1l, 258, 258, 64, 0, 2, w_e2h, w_e2l, eb2, 128, 128, 128, 2, 1, 130, 130, 1, a2h, a2l);
    conv_mfma<true, 64, true><<<dim3(256, 4), 256, 0, stream>>>(
        a2h, a2l, 130, 130, 128, 1, 2, w_e3h, w_e3l, eb3, 256, 64, 64, 2, 1, 66, 66, 1, a3h, a3l);
    conv_mfma<true, 64, true><<<dim3(64, 8), 256, 0, stream>>>(
        a3h, a3l, 66, 66, 256, 2, 2, w_e4h, w_e4l, eb4, 512, 32, 32, 2, 0, 32, 32, 0, a4h, a4l);
    conv_mfma<true, 64, false><<<dim3(64, 1), 256, 0, stream>>>(
        a4h, a4l, 32, 32, 512, 3, 1, w_pqh, w_pql, pqb, 64, 32, 32, 0, 0, 32, 32, 0, zqH, nullptr);
    vq_knl<<<4096, 256, 0, stream>>>(zqH, w_embT, emb, qb + (size_t)h * 262144,
                                     loss + (size_t)h * 262144, 1024);
  }

  // post-quant 1x1 (full batch) -> padded 34x34x512
  bz(poqO, 8, 34, 34, 512);
  bz(u1h_, 4, 66, 66, 512);
  conv_mfma<false, 128, false><<<dim3(64, 8), 256, 0, stream>>>(
      qb, nullptr, 32, 32, 64, 0, 1, w_poq, nullptr, poqb, 512, 32, 32, 1, 1, 34, 34, 0, poqO, nullptr);

  // ---------- decoder, two batch-halves ----------
  for (int h = 0; h < 2; ++h) {
    bf16* pin = poqO + (size_t)h * 4 * 34 * 34 * 512;
    float* oout = out0 + (size_t)h * 786432;
    conv_mfma<false, 128, true><<<dim3(32, 8), 256, 0, stream>>>(
        pin, nullptr, 34, 34, 512, 3, 1, w_d1, nullptr, db1, 512, 32, 32, 1, 0, 32, 32, 1, c1h_, nullptr);
    up2_knl<<<G1(4l * 64 * 64 * 128), 256, 0, stream>>>(c1h_, u1h_, 4, 32, 32, 512);
    conv_mfma<false, 128, true><<<dim3(128, 4), 256, 0, stream>>>(
        u1h_, nullptr, 66, 66, 512, 3, 1, w_d2, nullptr, db2, 256, 64, 64, 1, 0, 64, 64, 1, c2h_, nullptr);
    bz(u2h_, 4, 130, 130, 256);
    up2_knl<<<G1(4l * 128 * 128 * 64), 256, 0, stream>>>(c2h_, u2h_, 4, 64, 64, 256);
    conv_mfma<false, 128, true><<<dim3(512, 2), 256, 0, stream>>>(
        u2h_, nullptr, 130, 130, 256, 2, 1, w_d3, nullptr, db3, 128, 128, 128, 1, 0, 128, 128, 1, c3h_, nullptr);
    bz(u3h_, 4, 258, 258, 128);
    up2_knl<<<G1(4l * 256 * 256 * 32), 256, 0, stream>>>(c3h_, u3h_, 4, 128, 128, 128);
    bz(c4h_, 4, 258, 258, 64);
    conv_mfma<false, 128, true><<<dim3(2048, 1), 256, 0, stream>>>(
        u3h_, nullptr, 258, 258, 128, 1, 1, w_d4, nullptr, db4, 64, 256, 256, 1, 1, 258, 258, 0, c4h_, nullptr);
    outc_knl<<<3072, 256, 0, stream>>>(c4h_, w_ow, ob, oout);
  }
}

// Round 4
// 1585.146 us; speedup vs baseline: 18.6902x; 1.1193x over previous
//
#include <hip/hip_runtime.h>
#include <hip/hip_bf16.h>
#include <math.h>

typedef __hip_bfloat16 bf16;
typedef __attribute__((ext_vector_type(8))) short short8;
typedef __attribute__((ext_vector_type(4))) float f32x4;

// ---------- scalar helpers ----------
static __device__ __forceinline__ float bf2f(unsigned short u) {
  return __uint_as_float(((unsigned int)u) << 16);
}
static __device__ __forceinline__ unsigned short f2bf_bits(float f) {
  unsigned int x = __float_as_uint(f);
  x += 0x7fffu + ((x >> 16) & 1u);  // RNE
  return (unsigned short)(x >> 16);
}
static __device__ __forceinline__ void sto_bf(bf16* p, float v) {
  *reinterpret_cast<unsigned short*>(p) = f2bf_bits(v);
}
struct F4 { float a, b, c, d; };
static __device__ __forceinline__ F4 ld4bf(const bf16* p) {
  uint2 u = *reinterpret_cast<const uint2*>(p);
  return { bf2f((unsigned short)(u.x & 0xffffu)), bf2f((unsigned short)(u.x >> 16)),
           bf2f((unsigned short)(u.y & 0xffffu)), bf2f((unsigned short)(u.y >> 16)) };
}

// async global->LDS, 16B per lane
static __device__ __forceinline__ void g2l16(const void* g, void* l) {
  __builtin_amdgcn_global_load_lds(
      (const __attribute__((address_space(1))) unsigned int*)g,
      (__attribute__((address_space(3))) unsigned int*)l, 16, 0, 0);
}

// ---------- weight transforms ----------
// OIHW f32 -> [tap][oc][ic] bf16 hi (+ optional lo residual)
__global__ __launch_bounds__(256) void wx_toc(const float* __restrict__ src,
                                              bf16* __restrict__ hi, bf16* __restrict__ lo,
                                              int OC, int IC, int T) {
  int total = T * OC * IC;
  int i = blockIdx.x * 256 + threadIdx.x;
  if (i >= total) return;
  int tap = i / (OC * IC); int r = i - tap * OC * IC;
  int oc = r / IC; int ic = r - oc * IC;
  float v = src[(oc * IC + ic) * T + tap];
  float h = bf2f(f2bf_bits(v));
  sto_bf(hi + i, h);
  if (lo) sto_bf(lo + i, v - h);
}
// OIHW f32 -> [tap][ic][oc] f32 (for direct-conv kernels)
__global__ __launch_bounds__(256) void wx_tico(const float* __restrict__ src,
                                               float* __restrict__ dst,
                                               int OC, int IC, int T) {
  int total = T * OC * IC;
  int i = blockIdx.x * 256 + threadIdx.x;
  if (i >= total) return;
  int tap = i / (IC * OC); int r = i - tap * IC * OC;
  int ic = r / OC; int oc = r - ic * OC;
  dst[i] = src[(oc * IC + ic) * T + tap];
}
// emb [1024][64] -> embT [64][1024]
__global__ __launch_bounds__(256) void wx_embT(const float* __restrict__ src, float* __restrict__ dst) {
  int i = blockIdx.x * 256 + threadIdx.x;
  if (i >= 65536) return;
  int d = i >> 10, k = i & 1023;
  dst[i] = src[k * 64 + d];
}

// ---------- zero the 1-px border of a padded NHWC bf16 tensor ----------
__global__ __launch_bounds__(256) void bzero_knl(bf16* __restrict__ buf, int N, int Hp, int Wp, int C) {
  long per = 2 * Wp + 2 * Hp - 4;
  long total = (long)N * per * C;
  long t = (long)blockIdx.x * 256 + threadIdx.x;
  if (t >= total) return;
  int c = (int)(t % C); long q = t / C;
  int pos = (int)(q % per); int n = (int)(q / per);
  int y, x;
  if (pos < Wp) { y = 0; x = pos; }
  else if (pos < 2 * Wp) { y = Hp - 1; x = pos - Wp; }
  else { int r = pos - 2 * Wp; y = 1 + (r >> 1); x = (r & 1) ? Wp - 1 : 0; }
  *reinterpret_cast<unsigned short*>(&buf[(((long)n * Hp + y) * Wp + x) * C + c]) = 0;
}

// ---------- MFMA implicit-GEMM conv ----------
// NHWC input (padded by 1 when TAP9), weights [tap][oc][ic] bf16.
// Block: 256 thr = 4 waves; tile BM x 64(oc), BK=64.
//   BM=128 (plain): waves stacked in M, each 32x64 (MREP2 x NREP4).
//   BM=64 (split hi/lo input+weights, 3-MFMA compensation): waves 2x2, each 32x32.
// LDS tiles XOR-swizzled (T2) via pre-swizzled GLOBAL source (rule #21),
// linear global_load_lds destinations.
// omode: 0 = f32 plain [p][OC]; 1 = bf16 (opt padded); 2 = bf16 hi/lo split (padded).
template <bool SPLIT, int BM, bool TAP9>
__global__ __launch_bounds__(256) void conv_mfma(
    const bf16* __restrict__ inhi, const bf16* __restrict__ inlo,
    int IHp, int IWp, int IC, int kcLog, int stride,
    const bf16* __restrict__ whi, const bf16* __restrict__ wlo,
    const float* __restrict__ bias, int OC, int OH, int OW,
    int omode, int opad, int OHp, int OWp, int silu,
    void* __restrict__ outp, bf16* __restrict__ outlo)
{
  constexpr int NB = SPLIT ? 2 : 1;
  constexpr int AIW = BM / 32;        // A stage instrs per wave
  constexpr int MREP = 2;
  constexpr int NREP = (BM == 128) ? 4 : 2;
  __shared__ uint4 ldsA[2][NB][BM * 8];
  __shared__ uint4 ldsB[2][NB][64 * 8];

  const int tid = threadIdx.x;
  const int lane = tid & 63;
  const int wv = tid >> 6;
  const int pixBase = blockIdx.x * BM;
  const int ocBase = blockIdx.y * 64;
  const int OHW = OH * OW;

  int aoff[AIW], asl[AIW];
#pragma unroll
  for (int j = 0; j < AIW; ++j) {
    int I = wv * AIW + j;
    int m = I * 8 + (lane >> 3);
    int icoff = ((lane & 7) ^ (m & 7)) * 8;   // swizzled source chunk
    int p = pixBase + m;
    int n = p / OHW; int r = p - n * OHW;
    int oy = r / OW; int ox = r - oy * OW;
    aoff[j] = ((n * IHp + oy * stride) * IWp + ox * stride) * IC + icoff;
    asl[j] = I * 64 + lane;
  }
  int boff[2], bsl[2];
#pragma unroll
  for (int j = 0; j < 2; ++j) {
    int I = wv * 2 + j;
    int ocr = I * 8 + (lane >> 3);
    int icoff = ((lane & 7) ^ (ocr & 7)) * 8;
    boff[j] = (ocBase + ocr) * IC + icoff;
    bsl[j] = I * 64 + lane;
  }

  const int kcMask = (1 << kcLog) - 1;
  const int steps = (TAP9 ? 9 : 1) << kcLog;

  auto stage = [&](int buf, int s) {
    int tap = s >> kcLog;
    int k0 = (s & kcMask) << 6;
    int ta = 0;
    if (TAP9) { int ky = tap / 3, kx = tap - ky * 3; ta = (ky * IWp + kx) * IC; }
    int ga = ta + k0;
#pragma unroll
    for (int j = 0; j < AIW; ++j) {
      g2l16(inhi + aoff[j] + ga, &ldsA[buf][0][asl[j]]);
      if constexpr (SPLIT) g2l16(inlo + aoff[j] + ga, &ldsA[buf][1][asl[j]]);
    }
    int gb = tap * OC * IC + k0;
#pragma unroll
    for (int j = 0; j < 2; ++j) {
      g2l16(whi + boff[j] + gb, &ldsB[buf][0][bsl[j]]);
      if constexpr (SPLIT) g2l16(wlo + boff[j] + gb, &ldsB[buf][1][bsl[j]]);
    }
  };

  const int wrow = (BM == 128) ? wv * 32 : (wv >> 1) * 32;
  const int wcol = (BM == 128) ? 0 : (wv & 1) * 32;

  f32x4 acc[MREP][NREP];
#pragma unroll
  for (int i = 0; i < MREP; ++i)
#pragma unroll
    for (int j = 0; j < NREP; ++j) { acc[i][j][0] = 0.f; acc[i][j][1] = 0.f; acc[i][j][2] = 0.f; acc[i][j][3] = 0.f; }

  stage(0, 0);
  __syncthreads();
  int cur = 0;
  for (int s = 0; s < steps; ++s) {
    if (s + 1 < steps) stage(cur ^ 1, s + 1);   // prefetch next tile (overlaps compute)
#pragma unroll
    for (int kk = 0; kk < 2; ++kk) {
      int kb = kk * 4 + (lane >> 4);
      short8 af[NB][MREP], bfr[NB][NREP];
#pragma unroll
      for (int mr = 0; mr < MREP; ++mr) {
        int row = wrow + mr * 16 + (lane & 15);
        int slot = row * 8 + (kb ^ (row & 7));
        af[0][mr] = *(const short8*)&ldsA[cur][0][slot];
        if constexpr (SPLIT) af[1][mr] = *(const short8*)&ldsA[cur][1][slot];
      }
#pragma unroll
      for (int nr = 0; nr < NREP; ++nr) {
        int ocr = wcol + nr * 16 + (lane & 15);
        int slot = ocr * 8 + (kb ^ (ocr & 7));
        bfr[0][nr] = *(const short8*)&ldsB[cur][0][slot];
        if constexpr (SPLIT) bfr[1][nr] = *(const short8*)&ldsB[cur][1][slot];
      }
#pragma unroll
      for (int mr = 0; mr < MREP; ++mr)
#pragma unroll
        for (int nr = 0; nr < NREP; ++nr) {
          acc[mr][nr] = __builtin_amdgcn_mfma_f32_16x16x32_bf16(af[0][mr], bfr[0][nr], acc[mr][nr], 0, 0, 0);
          if constexpr (SPLIT) {
            acc[mr][nr] = __builtin_amdgcn_mfma_f32_16x16x32_bf16(af[1][mr], bfr[0][nr], acc[mr][nr], 0, 0, 0);
            acc[mr][nr] = __builtin_amdgcn_mfma_f32_16x16x32_bf16(af[0][mr], bfr[1][nr], acc[mr][nr], 0, 0, 0);
          }
        }
    }
    __syncthreads();
    cur ^= 1;
  }

  // epilogue: C/D layout col=lane&15, row=(lane>>4)*4+reg (m89-verified)
#pragma unroll
  for (int mr = 0; mr < MREP; ++mr) {
#pragma unroll
    for (int nr = 0; nr < NREP; ++nr) {
      int col = ocBase + wcol + nr * 16 + (lane & 15);
      float bv = bias[col];
#pragma unroll
      for (int r = 0; r < 4; ++r) {
        int row = wrow + mr * 16 + (lane >> 4) * 4 + r;
        float v = acc[mr][nr][r] + bv;
        if (silu) v = v / (1.f + expf(-v));
        int p = pixBase + row;
        if (omode == 0) {
          ((float*)outp)[p * OC + col] = v;
        } else {
          int n = p / OHW; int rr = p - n * OHW;
          int oy = rr / OW; int ox = rr - oy * OW;
          int ob = ((n * OHp + oy + opad) * OWp + ox + opad) * OC + col;
          float h = bf2f(f2bf_bits(v));
          sto_bf((bf16*)outp + ob, h);
          if (omode == 2) sto_bf(outlo + ob, v - h);
        }
      }
    }
  }
}

// ---------- e1 v2: 3->64 3x3 direct f32, silu, split hi/lo to padded NHWC ----------
// wave = 64 lanes = oc; each thread computes 4 adjacent x-pixels.
// 27 weights hoisted to VGPRs; x loads wave-uniform (broadcast).
__global__ __launch_bounds__(256) void e1_knl(const float* __restrict__ x,  // 4 imgs NCHW
                                              const float* __restrict__ w,  // [tap][3][64]
                                              const float* __restrict__ bias,
                                              bf16* __restrict__ ahi, bf16* __restrict__ alo) {
  int gw = (blockIdx.x << 2) | (threadIdx.x >> 6);   // wave id: 4*256*64 = 65536
  int lane = threadIdx.x & 63;
  int ox0 = (gw & 63) << 2;
  int oy = (gw >> 6) & 255;
  int n = gw >> 14;

  float wr[27];
#pragma unroll
  for (int j = 0; j < 27; ++j) wr[j] = w[j * 64 + lane];

  float bv = bias[lane];
  float acc[4] = {bv, bv, bv, bv};

#pragma unroll
  for (int ky = 0; ky < 3; ++ky) {
    int iy = oy - 1 + ky;
    if ((unsigned)iy < 256u) {
#pragma unroll
      for (int ic = 0; ic < 3; ++ic) {
        const float* xr = x + ((n * 3 + ic) * 256 + iy) * 256;
        float xv[6];
#pragma unroll
        for (int j = 0; j < 6; ++j) {
          int ix = ox0 - 1 + j;
          xv[j] = ((unsigned)ix < 256u) ? xr[ix] : 0.f;
        }
#pragma unroll
        for (int kx = 0; kx < 3; ++kx) {
          float wv = wr[(ky * 3 + kx) * 3 + ic];
#pragma unroll
          for (int p = 0; p < 4; ++p) acc[p] = fmaf(xv[p + kx], wv, acc[p]);
        }
      }
    }
  }
#pragma unroll
  for (int p = 0; p < 4; ++p) {
    float v = acc[p] / (1.f + __expf(-acc[p]));
    long ob = (((long)n * 258 + oy + 1) * 258 + (ox0 + p + 1)) * 64 + lane;
    float h = bf2f(f2bf_bits(v));
    sto_bf(ahi + ob, h);
    sto_bf(alo + ob, v - h);
  }
}

// ---------- bilinear 2x upsample, unpadded in -> padded out interior ----------
__global__ __launch_bounds__(256) void up2_knl(const bf16* __restrict__ in, bf16* __restrict__ out,
                                               int N, int H, int W, int C) {
  int C4 = C >> 2;
  int OW = 2 * W, OH = 2 * H;
  long total = (long)N * OH * OW * C4;
  long tid = (long)blockIdx.x * 256 + threadIdx.x;
  if (tid >= total) return;
  int c4 = (int)(tid % C4); long t = tid / C4;
  int ox = (int)(t % OW); t /= OW;
  int oy = (int)(t % OH); int n = (int)(t / OH);
  float sy = 0.5f * oy - 0.25f, sx = 0.5f * ox - 0.25f;
  int y0 = (int)floorf(sy); float fy = sy - (float)y0;
  int x0 = (int)floorf(sx); float fx = sx - (float)x0;
  int y0c = y0 < 0 ? 0 : y0; int y1c = (y0 + 1 > H - 1) ? (H - 1) : (y0 + 1);
  int x0c = x0 < 0 ? 0 : x0; int x1c = (x0 + 1 > W - 1) ? (W - 1) : (x0 + 1);
  const bf16* base = in + (long)n * H * W * C + c4 * 4;
  F4 t00 = ld4bf(base + ((long)y0c * W + x0c) * C);
  F4 t01 = ld4bf(base + ((long)y0c * W + x1c) * C);
  F4 t10 = ld4bf(base + ((long)y1c * W + x0c) * C);
  F4 t11 = ld4bf(base + ((long)y1c * W + x1c) * C);
  float w00 = (1.f - fy) * (1.f - fx), w01 = (1.f - fy) * fx;
  float w10 = fy * (1.f - fx), w11 = fy * fx;
  union { unsigned short us[4]; uint2 u; } pk;
  pk.us[0] = f2bf_bits(w00 * t00.a + w01 * t01.a + w10 * t10.a + w11 * t11.a);
  pk.us[1] = f2bf_bits(w00 * t00.b + w01 * t01.b + w10 * t10.b + w11 * t11.b);
  pk.us[2] = f2bf_bits(w00 * t00.c + w01 * t01.c + w10 * t10.c + w11 * t11.c);
  pk.us[3] = f2bf_bits(w00 * t00.d + w01 * t01.d + w10 * t10.d + w11 * t11.d);
  *reinterpret_cast<uint2*>(out + (((long)n * (OH + 2) + oy + 1) * (OW + 2) + ox + 1) * C + c4 * 4) = pk.u;
}

// ---------- VQ: per-row argmin over 1024 codes, D=64 ----------
__global__ __launch_bounds__(256) void vq_knl(const float* __restrict__ zq,
                                              const float* __restrict__ embT,  // [64][1024]
                                              const float* __restrict__ emb,   // [1024][64]
                                              bf16* __restrict__ q,
                                              float* __restrict__ loss, int K) {
  __shared__ float z[64];
  __shared__ float sd[256];
  __shared__ int si[256];
  int row = blockIdx.x;
  int tid = threadIdx.x;
  if (tid < 64) z[tid] = zq[(long)row * 64 + tid];
  __syncthreads();
  float best = 3.4e38f; int bi = 0;
  for (int k = tid; k < K; k += 256) {
    float d2 = 0.f;
#pragma unroll
    for (int d = 0; d < 64; ++d) {
      float diff = embT[d * K + k] - z[d];
      d2 = fmaf(diff, diff, d2);
    }
    if (d2 < best) { best = d2; bi = k; }
  }
  sd[tid] = best; si[tid] = bi;
  __syncthreads();
  for (int s = 128; s > 0; s >>= 1) {
    if (tid < s) {
      float od = sd[tid + s]; int oi = si[tid + s];
      if (od < sd[tid] || (od == sd[tid] && oi < si[tid])) { sd[tid] = od; si[tid] = oi; }
    }
    __syncthreads();
  }
  int idx = si[0];
  if (tid < 64) {
    float e = emb[(long)idx * 64 + tid];
    float diff = e - z[tid];
    sto_bf(q + (long)row * 64 + tid, e);
    loss[(long)row * 64 + tid] = 1.25f * diff * diff;
  }
}

// ---------- outc v2: 3x3 conv (64->3)+sigmoid; 1 thread/pixel, 3 ch; scalar weights ----------
__global__ __launch_bounds__(256) void outc_knl(const bf16* __restrict__ in,   // [4][258][258][64]
                                                const float* __restrict__ w,   // [tap][64][3]
                                                const float* __restrict__ bias,
                                                float* __restrict__ out) {     // [4][3][256][256]
  int pix = blockIdx.x * 256 + threadIdx.x;   // 262144 per half
  int x = pix & 255;
  int y = (pix >> 8) & 255;
  int n = pix >> 16;
  float a0 = bias[0], a1 = bias[1], a2 = bias[2];
#pragma unroll
  for (int ky = 0; ky < 3; ++ky) {
#pragma unroll
    for (int kx = 0; kx < 3; ++kx) {
      const bf16* ip = in + (((long)(n * 258 + y + ky)) * 258 + (x + kx)) * 64;
      const int t = ky * 3 + kx;
#pragma unroll
      for (int g = 0; g < 8; ++g) {
        short8 v = *reinterpret_cast<const short8*>(ip + g * 8);
#pragma unroll
        for (int j = 0; j < 8; ++j) {
          float f = bf2f((unsigned short)v[j]);
          int ic = g * 8 + j;
          a0 = fmaf(f, w[(t * 64 + ic) * 3 + 0], a0);   // uniform addr -> s_load
          a1 = fmaf(f, w[(t * 64 + ic) * 3 + 1], a1);
          a2 = fmaf(f, w[(t * 64 + ic) * 3 + 2], a2);
        }
      }
    }
  }
  long ob = ((long)n * 3) * 65536 + ((long)y << 8) + x;
  out[ob]          = 1.f / (1.f + __expf(-a0));
  out[ob + 65536]  = 1.f / (1.f + __expf(-a1));
  out[ob + 131072] = 1.f / (1.f + __expf(-a2));
}

// ---------- host ----------
extern "C" void kernel_launch(void* const* d_in, const int* in_sizes, int n_in,
                              void* d_out, int out_size, void* d_ws, size_t ws_size,
                              hipStream_t stream) {
  (void)in_sizes; (void)n_in; (void)out_size; (void)ws_size;
  const float* x    = (const float*)d_in[0];
  const float* ew1  = (const float*)d_in[1];  const float* eb1 = (const float*)d_in[2];
  const float* ew2  = (const float*)d_in[3];  const float* eb2 = (const float*)d_in[4];
  const float* ew3  = (const float*)d_in[5];  const float* eb3 = (const float*)d_in[6];
  const float* ew4  = (const float*)d_in[7];  const float* eb4 = (const float*)d_in[8];
  const float* pqw  = (const float*)d_in[9];  const float* pqb = (const float*)d_in[10];
  const float* emb  = (const float*)d_in[11];
  const float* poqw = (const float*)d_in[12]; const float* poqb = (const float*)d_in[13];
  const float* dw1  = (const float*)d_in[14]; const float* db1 = (const float*)d_in[15];
  const float* dw2  = (const float*)d_in[16]; const float* db2 = (const float*)d_in[17];
  const float* dw3  = (const float*)d_in[18]; const float* db3 = (const float*)d_in[19];
  const float* dw4  = (const float*)d_in[20]; const float* db4 = (const float*)d_in[21];
  const float* oww  = (const float*)d_in[22]; const float* ob  = (const float*)d_in[23];

  char* wsb = (char*)d_ws;
  size_t off = 0;
  auto alloc = [&](size_t b) -> char* {
    char* p = wsb + off;
    off = (off + b + 255) & ~(size_t)255;
    return p;
  };

  float* w_e1   = (float*)alloc(1728 * 4);
  float* w_ow   = (float*)alloc(1728 * 4);
  float* w_embT = (float*)alloc(65536 * 4);
  bf16* w_e2h = (bf16*)alloc(73728 * 2);   bf16* w_e2l = (bf16*)alloc(73728 * 2);
  bf16* w_e3h = (bf16*)alloc(294912 * 2);  bf16* w_e3l = (bf16*)alloc(294912 * 2);
  bf16* w_e4h = (bf16*)alloc(1179648 * 2); bf16* w_e4l = (bf16*)alloc(1179648 * 2);
  bf16* w_pqh = (bf16*)alloc(32768 * 2);   bf16* w_pql = (bf16*)alloc(32768 * 2);
  bf16* w_poq = (bf16*)alloc(32768 * 2);
  bf16* w_d1  = (bf16*)alloc(2359296 * 2);
  bf16* w_d2  = (bf16*)alloc(1179648 * 2);
  bf16* w_d3  = (bf16*)alloc(294912 * 2);
  bf16* w_d4  = (bf16*)alloc(73728 * 2);

  char* RA = alloc(68161536);   // [a1h|a1l] (enc half) -> u3h (dec half)
  char* RB = alloc(68161536);   // enc-half overlay -> decoder arena
  char* RC = alloc(28360704);   // qb | poqO | u1h

  // --- encoder-half overlays in RA/RB ---
  bf16* a1h = (bf16*)RA;                       // 4*258*258*64*2 = 34,080,768
  bf16* a1l = (bf16*)(RA + 34080768);
  bf16* u3h_ = (bf16*)RA;                      // 4*258*258*128*2 = 68,161,536 (decoder)

  bf16* a2h = (bf16*)RB;                       // 4*130*130*128*2 = 17,305,600
  bf16* a2l = (bf16*)(RB + 17305600);
  bf16* a3h = (bf16*)(RB + 34611200);          // 4*66*66*256*2 = 8,921,088
  bf16* a3l = (bf16*)(RB + 43532288);
  bf16* a4h = (bf16*)(RB + 52453376);          // 4*32*32*512*2 = 4,194,304
  bf16* a4l = (bf16*)(RB + 56647680);
  float* zqH = (float*)(RB + 60841984);        // 4096*64*4 = 1,048,576

  // --- decoder overlay in RB (per half) ---
  bf16* u2h_ = (bf16*)RB;                      // 4*130*130*256*2 = 34,611,200
  bf16* c4h_ = (bf16*)RB;                      // 4*258*258*64*2 = 34,080,768
  bf16* c3h_ = (bf16*)(RB + 34611200);         // 4*128*128*128*2 = 16,777,216
  bf16* c2h_ = (bf16*)(RB + 51388416);         // 4*64*64*256*2 = 8,388,608
  bf16* c1h_ = (bf16*)(RB + 59777024);         // 4*32*32*512*2 = 4,194,304

  // --- RC overlays ---
  bf16* qb   = (bf16*)RC;                      // 8192*64*2 = 1,048,576 (full batch)
  bf16* poqO = (bf16*)(RC + 1048576);          // 8*34*34*512*2 = 9,469,952
  bf16* u1h_ = (bf16*)(RC + 10518528);         // 4*66*66*512*2 = 17,842,176

  float* out0 = (float*)d_out;
  float* loss = out0 + 1572864;

  auto G1 = [](long n) { return dim3((unsigned)((n + 255) / 256)); };

  // weight transforms
  wx_tico<<<G1(1728), 256, 0, stream>>>(ew1, w_e1, 64, 3, 9);
  wx_tico<<<G1(1728), 256, 0, stream>>>(oww, w_ow, 3, 64, 9);
  wx_embT<<<G1(65536), 256, 0, stream>>>(emb, w_embT);
  wx_toc<<<G1(73728), 256, 0, stream>>>(ew2, w_e2h, w_e2l, 128, 64, 9);
  wx_toc<<<G1(294912), 256, 0, stream>>>(ew3, w_e3h, w_e3l, 256, 128, 9);
  wx_toc<<<G1(1179648), 256, 0, stream>>>(ew4, w_e4h, w_e4l, 512, 256, 9);
  wx_toc<<<G1(32768), 256, 0, stream>>>(pqw, w_pqh, w_pql, 64, 512, 1);
  wx_toc<<<G1(32768), 256, 0, stream>>>(poqw, w_poq, (bf16*)nullptr, 512, 64, 1);
  wx_toc<<<G1(2359296), 256, 0, stream>>>(dw1, w_d1, (bf16*)nullptr, 512, 512, 9);
  wx_toc<<<G1(1179648), 256, 0, stream>>>(dw2, w_d2, (bf16*)nullptr, 256, 512, 9);
  wx_toc<<<G1(294912), 256, 0, stream>>>(dw3, w_d3, (bf16*)nullptr, 128, 256, 9);
  wx_toc<<<G1(73728), 256, 0, stream>>>(dw4, w_d4, (bf16*)nullptr, 64, 128, 9);

  auto bz = [&](bf16* p, int N, int Hp, int Wp, int C) {
    long tot = (long)N * (2 * Wp + 2 * Hp - 4) * C;
    bzero_knl<<<G1(tot), 256, 0, stream>>>(p, N, Hp, Wp, C);
  };
  // borders for encoder-half buffers (interiors fully rewritten each half)
  bz(a1h, 4, 258, 258, 64); bz(a1l, 4, 258, 258, 64);
  bz(a2h, 4, 130, 130, 128); bz(a2l, 4, 130, 130, 128);
  bz(a3h, 4, 66, 66, 256);   bz(a3l, 4, 66, 66, 256);

  // ---------- encoder + VQ, two batch-halves ----------
  for (int h = 0; h < 2; ++h) {
    const float* xh = x + (size_t)h * 786432;  // 4 images NCHW
    e1_knl<<<16384, 256, 0, stream>>>(xh, w_e1, eb1, a1h, a1l);
    conv_mfma<true, 64, true><<<dim3(1024, 2), 256, 0, stream>>>(
        a1h, a1l, 258, 258, 64, 0, 2, w_e2h, w_e2l, eb2, 128, 128, 128, 2, 1, 130, 130, 1, a2h, a2l);
    conv_mfma<true, 64, true><<<dim3(256, 4), 256, 0, stream>>>(
        a2h, a2l, 130, 130, 128, 1, 2, w_e3h, w_e3l, eb3, 256, 64, 64, 2, 1, 66, 66, 1, a3h, a3l);
    conv_mfma<true, 64, true><<<dim3(64, 8), 256, 0, stream>>>(
        a3h, a3l, 66, 66, 256, 2, 2, w_e4h, w_e4l, eb4, 512, 32, 32, 2, 0, 32, 32, 0, a4h, a4l);
    conv_mfma<true, 64, false><<<dim3(64, 1), 256, 0, stream>>>(
        a4h, a4l, 32, 32, 512, 3, 1, w_pqh, w_pql, pqb, 64, 32, 32, 0, 0, 32, 32, 0, zqH, nullptr);
    vq_knl<<<4096, 256, 0, stream>>>(zqH, w_embT, emb, qb + (size_t)h * 262144,
                                     loss + (size_t)h * 262144, 1024);
  }

  // post-quant 1x1 (full batch) -> padded 34x34x512
  bz(poqO, 8, 34, 34, 512);
  bz(u1h_, 4, 66, 66, 512);
  conv_mfma<false, 128, false><<<dim3(64, 8), 256, 0, stream>>>(
      qb, nullptr, 32, 32, 64, 0, 1, w_poq, nullptr, poqb, 512, 32, 32, 1, 1, 34, 34, 0, poqO, nullptr);

  // ---------- decoder, two batch-halves ----------
  for (int h = 0; h < 2; ++h) {
    bf16* pin = poqO + (size_t)h * 4 * 34 * 34 * 512;
    float* oout = out0 + (size_t)h * 786432;
    conv_mfma<false, 128, true><<<dim3(32, 8), 256, 0, stream>>>(
        pin, nullptr, 34, 34, 512, 3, 1, w_d1, nullptr, db1, 512, 32, 32, 1, 0, 32, 32, 1, c1h_, nullptr);
    up2_knl<<<G1(4l * 64 * 64 * 128), 256, 0, stream>>>(c1h_, u1h_, 4, 32, 32, 512);
    conv_mfma<false, 128, true><<<dim3(128, 4), 256, 0, stream>>>(
        u1h_, nullptr, 66, 66, 512, 3, 1, w_d2, nullptr, db2, 256, 64, 64, 1, 0, 64, 64, 1, c2h_, nullptr);
    bz(u2h_, 4, 130, 130, 256);
    up2_knl<<<G1(4l * 128 * 128 * 64), 256, 0, stream>>>(c2h_, u2h_, 4, 64, 64, 256);
    conv_mfma<false, 128, true><<<dim3(512, 2), 256, 0, stream>>>(
        u2h_, nullptr, 130, 130, 256, 2, 1, w_d3, nullptr, db3, 128, 128, 128, 1, 0, 128, 128, 1, c3h_, nullptr);
    bz(u3h_, 4, 258, 258, 128);
    up2_knl<<<G1(4l * 256 * 256 * 32), 256, 0, stream>>>(c3h_, u3h_, 4, 128, 128, 128);
    bz(c4h_, 4, 258, 258, 64);
    conv_mfma<false, 128, true><<<dim3(2048, 1), 256, 0, stream>>>(
        u3h_, nullptr, 258, 258, 128, 1, 1, w_d4, nullptr, db4, 64, 256, 256, 1, 1, 258, 258, 0, c4h_, nullptr);
    outc_knl<<<1024, 256, 0, stream>>>(c4h_, w_ow, ob, oout);
  }
}

// Round 5
// 1412.582 us; speedup vs baseline: 20.9734x; 1.1222x over previous
//
#include <hip/hip_runtime.h>
#include <hip/hip_bf16.h>
#include <math.h>

typedef __hip_bfloat16 bf16;
typedef __attribute__((ext_vector_type(8))) short short8;
typedef __attribute__((ext_vector_type(4))) float f32x4;

// ---------- scalar helpers ----------
static __device__ __forceinline__ float bf2f(unsigned short u) {
  return __uint_as_float(((unsigned int)u) << 16);
}
static __device__ __forceinline__ unsigned short f2bf_bits(float f) {
  unsigned int x = __float_as_uint(f);
  x += 0x7fffu + ((x >> 16) & 1u);  // RNE
  return (unsigned short)(x >> 16);
}
static __device__ __forceinline__ void sto_bf(bf16* p, float v) {
  *reinterpret_cast<unsigned short*>(p) = f2bf_bits(v);
}
struct F4 { float a, b, c, d; };
static __device__ __forceinline__ F4 ld4bf(const bf16* p) {
  uint2 u = *reinterpret_cast<const uint2*>(p);
  return { bf2f((unsigned short)(u.x & 0xffffu)), bf2f((unsigned short)(u.x >> 16)),
           bf2f((unsigned short)(u.y & 0xffffu)), bf2f((unsigned short)(u.y >> 16)) };
}

// async global->LDS, 16B per lane
static __device__ __forceinline__ void g2l16(const void* g, void* l) {
  __builtin_amdgcn_global_load_lds(
      (const __attribute__((address_space(1))) unsigned int*)g,
      (__attribute__((address_space(3))) unsigned int*)l, 16, 0, 0);
}

// ---------- weight transforms ----------
// OIHW f32 -> [tap][oc][ic] bf16 hi (+ optional lo residual)
__global__ __launch_bounds__(256) void wx_toc(const float* __restrict__ src,
                                              bf16* __restrict__ hi, bf16* __restrict__ lo,
                                              int OC, int IC, int T) {
  int total = T * OC * IC;
  int i = blockIdx.x * 256 + threadIdx.x;
  if (i >= total) return;
  int tap = i / (OC * IC); int r = i - tap * OC * IC;
  int oc = r / IC; int ic = r - oc * IC;
  float v = src[(oc * IC + ic) * T + tap];
  float h = bf2f(f2bf_bits(v));
  sto_bf(hi + i, h);
  if (lo) sto_bf(lo + i, v - h);
}
// OIHW f32 -> [tap][ic][oc] f32 (for direct-conv kernels)
__global__ __launch_bounds__(256) void wx_tico(const float* __restrict__ src,
                                               float* __restrict__ dst,
                                               int OC, int IC, int T) {
  int total = T * OC * IC;
  int i = blockIdx.x * 256 + threadIdx.x;
  if (i >= total) return;
  int tap = i / (IC * OC); int r = i - tap * IC * OC;
  int ic = r / OC; int oc = r - ic * OC;
  dst[i] = src[(oc * IC + ic) * T + tap];
}

// ---------- zero the 1-px border of a padded NHWC bf16 tensor ----------
__global__ __launch_bounds__(256) void bzero_knl(bf16* __restrict__ buf, int N, int Hp, int Wp, int C) {
  long per = 2 * Wp + 2 * Hp - 4;
  long total = (long)N * per * C;
  long t = (long)blockIdx.x * 256 + threadIdx.x;
  if (t >= total) return;
  int c = (int)(t % C); long q = t / C;
  int pos = (int)(q % per); int n = (int)(q / per);
  int y, x;
  if (pos < Wp) { y = 0; x = pos; }
  else if (pos < 2 * Wp) { y = Hp - 1; x = pos - Wp; }
  else { int r = pos - 2 * Wp; y = 1 + (r >> 1); x = (r & 1) ? Wp - 1 : 0; }
  *reinterpret_cast<unsigned short*>(&buf[(((long)n * Hp + y) * Wp + x) * C + c]) = 0;
}

// ---------- MFMA implicit-GEMM conv ----------
// NHWC input (padded by 1 when TAP9), weights [tap][oc][ic] bf16.
// Block: 256 thr = 4 waves; tile BM x 64(oc), BK=64.
//   BM=128 (plain): waves stacked in M, each 32x64 (MREP2 x NREP4).
//   BM=64 (split hi/lo input+weights, 3-MFMA compensation): waves 2x2, each 32x32.
// LDS tiles XOR-swizzled (T2) via pre-swizzled GLOBAL source (rule #21),
// linear global_load_lds destinations.
// omode: 0 = f32 plain [p][OC]; 1 = bf16 (opt padded); 2 = bf16 hi/lo split (padded).
template <bool SPLIT, int BM, bool TAP9>
__global__ __launch_bounds__(256) void conv_mfma(
    const bf16* __restrict__ inhi, const bf16* __restrict__ inlo,
    int IHp, int IWp, int IC, int kcLog, int stride,
    const bf16* __restrict__ whi, const bf16* __restrict__ wlo,
    const float* __restrict__ bias, int OC, int OH, int OW,
    int omode, int opad, int OHp, int OWp, int silu,
    void* __restrict__ outp, bf16* __restrict__ outlo)
{
  constexpr int NB = SPLIT ? 2 : 1;
  constexpr int AIW = BM / 32;        // A stage instrs per wave
  constexpr int MREP = 2;
  constexpr int NREP = (BM == 128) ? 4 : 2;
  __shared__ uint4 ldsA[2][NB][BM * 8];
  __shared__ uint4 ldsB[2][NB][64 * 8];

  const int tid = threadIdx.x;
  const int lane = tid & 63;
  const int wv = tid >> 6;
  const int pixBase = blockIdx.x * BM;
  const int ocBase = blockIdx.y * 64;
  const int OHW = OH * OW;

  int aoff[AIW], asl[AIW];
#pragma unroll
  for (int j = 0; j < AIW; ++j) {
    int I = wv * AIW + j;
    int m = I * 8 + (lane >> 3);
    int icoff = ((lane & 7) ^ (m & 7)) * 8;   // swizzled source chunk
    int p = pixBase + m;
    int n = p / OHW; int r = p - n * OHW;
    int oy = r / OW; int ox = r - oy * OW;
    aoff[j] = ((n * IHp + oy * stride) * IWp + ox * stride) * IC + icoff;
    asl[j] = I * 64 + lane;
  }
  int boff[2], bsl[2];
#pragma unroll
  for (int j = 0; j < 2; ++j) {
    int I = wv * 2 + j;
    int ocr = I * 8 + (lane >> 3);
    int icoff = ((lane & 7) ^ (ocr & 7)) * 8;
    boff[j] = (ocBase + ocr) * IC + icoff;
    bsl[j] = I * 64 + lane;
  }

  const int kcMask = (1 << kcLog) - 1;
  const int steps = (TAP9 ? 9 : 1) << kcLog;

  auto stage = [&](int buf, int s) {
    int tap = s >> kcLog;
    int k0 = (s & kcMask) << 6;
    int ta = 0;
    if (TAP9) { int ky = tap / 3, kx = tap - ky * 3; ta = (ky * IWp + kx) * IC; }
    int ga = ta + k0;
#pragma unroll
    for (int j = 0; j < AIW; ++j) {
      g2l16(inhi + aoff[j] + ga, &ldsA[buf][0][asl[j]]);
      if constexpr (SPLIT) g2l16(inlo + aoff[j] + ga, &ldsA[buf][1][asl[j]]);
    }
    int gb = tap * OC * IC + k0;
#pragma unroll
    for (int j = 0; j < 2; ++j) {
      g2l16(whi + boff[j] + gb, &ldsB[buf][0][bsl[j]]);
      if constexpr (SPLIT) g2l16(wlo + boff[j] + gb, &ldsB[buf][1][bsl[j]]);
    }
  };

  const int wrow = (BM == 128) ? wv * 32 : (wv >> 1) * 32;
  const int wcol = (BM == 128) ? 0 : (wv & 1) * 32;

  f32x4 acc[MREP][NREP];
#pragma unroll
  for (int i = 0; i < MREP; ++i)
#pragma unroll
    for (int j = 0; j < NREP; ++j) { acc[i][j][0] = 0.f; acc[i][j][1] = 0.f; acc[i][j][2] = 0.f; acc[i][j][3] = 0.f; }

  stage(0, 0);
  __syncthreads();
  int cur = 0;
  for (int s = 0; s < steps; ++s) {
    if (s + 1 < steps) stage(cur ^ 1, s + 1);   // prefetch next tile (overlaps compute)
#pragma unroll
    for (int kk = 0; kk < 2; ++kk) {
      int kb = kk * 4 + (lane >> 4);
      short8 af[NB][MREP], bfr[NB][NREP];
#pragma unroll
      for (int mr = 0; mr < MREP; ++mr) {
        int row = wrow + mr * 16 + (lane & 15);
        int slot = row * 8 + (kb ^ (row & 7));
        af[0][mr] = *(const short8*)&ldsA[cur][0][slot];
        if constexpr (SPLIT) af[1][mr] = *(const short8*)&ldsA[cur][1][slot];
      }
#pragma unroll
      for (int nr = 0; nr < NREP; ++nr) {
        int ocr = wcol + nr * 16 + (lane & 15);
        int slot = ocr * 8 + (kb ^ (ocr & 7));
        bfr[0][nr] = *(const short8*)&ldsB[cur][0][slot];
        if constexpr (SPLIT) bfr[1][nr] = *(const short8*)&ldsB[cur][1][slot];
      }
#pragma unroll
      for (int mr = 0; mr < MREP; ++mr)
#pragma unroll
        for (int nr = 0; nr < NREP; ++nr) {
          acc[mr][nr] = __builtin_amdgcn_mfma_f32_16x16x32_bf16(af[0][mr], bfr[0][nr], acc[mr][nr], 0, 0, 0);
          if constexpr (SPLIT) {
            acc[mr][nr] = __builtin_amdgcn_mfma_f32_16x16x32_bf16(af[1][mr], bfr[0][nr], acc[mr][nr], 0, 0, 0);
            acc[mr][nr] = __builtin_amdgcn_mfma_f32_16x16x32_bf16(af[0][mr], bfr[1][nr], acc[mr][nr], 0, 0, 0);
          }
        }
    }
    __syncthreads();
    cur ^= 1;
  }

  // epilogue: C/D layout col=lane&15, row=(lane>>4)*4+reg (m89-verified)
#pragma unroll
  for (int mr = 0; mr < MREP; ++mr) {
#pragma unroll
    for (int nr = 0; nr < NREP; ++nr) {
      int col = ocBase + wcol + nr * 16 + (lane & 15);
      float bv = bias[col];
#pragma unroll
      for (int r = 0; r < 4; ++r) {
        int row = wrow + mr * 16 + (lane >> 4) * 4 + r;
        float v = acc[mr][nr][r] + bv;
        if (silu) v = v / (1.f + expf(-v));
        int p = pixBase + row;
        if (omode == 0) {
          ((float*)outp)[p * OC + col] = v;
        } else {
          int n = p / OHW; int rr = p - n * OHW;
          int oy = rr / OW; int ox = rr - oy * OW;
          int ob = ((n * OHp + oy + opad) * OWp + ox + opad) * OC + col;
          float h = bf2f(f2bf_bits(v));
          sto_bf((bf16*)outp + ob, h);
          if (omode == 2) sto_bf(outlo + ob, v - h);
        }
      }
    }
  }
}

// ---------- e1 v2: 3->64 3x3 direct f32, silu, split hi/lo to padded NHWC ----------
__global__ __launch_bounds__(256) void e1_knl(const float* __restrict__ x,  // 4 imgs NCHW
                                              const float* __restrict__ w,  // [tap][3][64]
                                              const float* __restrict__ bias,
                                              bf16* __restrict__ ahi, bf16* __restrict__ alo) {
  int gw = (blockIdx.x << 2) | (threadIdx.x >> 6);   // wave id: 4*256*64 = 65536
  int lane = threadIdx.x & 63;
  int ox0 = (gw & 63) << 2;
  int oy = (gw >> 6) & 255;
  int n = gw >> 14;

  float wr[27];
#pragma unroll
  for (int j = 0; j < 27; ++j) wr[j] = w[j * 64 + lane];

  float bv = bias[lane];
  float acc[4] = {bv, bv, bv, bv};

#pragma unroll
  for (int ky = 0; ky < 3; ++ky) {
    int iy = oy - 1 + ky;
    if ((unsigned)iy < 256u) {
#pragma unroll
      for (int ic = 0; ic < 3; ++ic) {
        const float* xr = x + ((n * 3 + ic) * 256 + iy) * 256;
        float xv[6];
#pragma unroll
        for (int j = 0; j < 6; ++j) {
          int ix = ox0 - 1 + j;
          xv[j] = ((unsigned)ix < 256u) ? xr[ix] : 0.f;
        }
#pragma unroll
        for (int kx = 0; kx < 3; ++kx) {
          float wv = wr[(ky * 3 + kx) * 3 + ic];
#pragma unroll
          for (int p = 0; p < 4; ++p) acc[p] = fmaf(xv[p + kx], wv, acc[p]);
        }
      }
    }
  }
#pragma unroll
  for (int p = 0; p < 4; ++p) {
    float v = acc[p] / (1.f + __expf(-acc[p]));
    long ob = (((long)n * 258 + oy + 1) * 258 + (ox0 + p + 1)) * 64 + lane;
    float h = bf2f(f2bf_bits(v));
    sto_bf(ahi + ob, h);
    sto_bf(alo + ob, v - h);
  }
}

// ---------- bilinear 2x upsample, unpadded in -> padded out interior ----------
__global__ __launch_bounds__(256) void up2_knl(const bf16* __restrict__ in, bf16* __restrict__ out,
                                               int N, int H, int W, int C) {
  int C4 = C >> 2;
  int OW = 2 * W, OH = 2 * H;
  long total = (long)N * OH * OW * C4;
  long tid = (long)blockIdx.x * 256 + threadIdx.x;
  if (tid >= total) return;
  int c4 = (int)(tid % C4); long t = tid / C4;
  int ox = (int)(t % OW); t /= OW;
  int oy = (int)(t % OH); int n = (int)(t / OH);
  float sy = 0.5f * oy - 0.25f, sx = 0.5f * ox - 0.25f;
  int y0 = (int)floorf(sy); float fy = sy - (float)y0;
  int x0 = (int)floorf(sx); float fx = sx - (float)x0;
  int y0c = y0 < 0 ? 0 : y0; int y1c = (y0 + 1 > H - 1) ? (H - 1) : (y0 + 1);
  int x0c = x0 < 0 ? 0 : x0; int x1c = (x0 + 1 > W - 1) ? (W - 1) : (x0 + 1);
  const bf16* base = in + (long)n * H * W * C + c4 * 4;
  F4 t00 = ld4bf(base + ((long)y0c * W + x0c) * C);
  F4 t01 = ld4bf(base + ((long)y0c * W + x1c) * C);
  F4 t10 = ld4bf(base + ((long)y1c * W + x0c) * C);
  F4 t11 = ld4bf(base + ((long)y1c * W + x1c) * C);
  float w00 = (1.f - fy) * (1.f - fx), w01 = (1.f - fy) * fx;
  float w10 = fy * (1.f - fx), w11 = fy * fx;
  union { unsigned short us[4]; uint2 u; } pk;
  pk.us[0] = f2bf_bits(w00 * t00.a + w01 * t01.a + w10 * t10.a + w11 * t11.a);
  pk.us[1] = f2bf_bits(w00 * t00.b + w01 * t01.b + w10 * t10.b + w11 * t11.b);
  pk.us[2] = f2bf_bits(w00 * t00.c + w01 * t01.c + w10 * t10.c + w11 * t11.c);
  pk.us[3] = f2bf_bits(w00 * t00.d + w01 * t01.d + w10 * t10.d + w11 * t11.d);
  *reinterpret_cast<uint2*>(out + (((long)n * (OH + 2) + oy + 1) * (OW + 2) + ox + 1) * C + c4 * 4) = pk.u;
}

// ---------- VQ v2 ----------
// zq f32 -> bf16 hi/lo split
__global__ __launch_bounds__(256) void zsplit_knl(const float* __restrict__ src,
                                                  bf16* __restrict__ hi, bf16* __restrict__ lo, int n) {
  int i = blockIdx.x * 256 + threadIdx.x;
  if (i >= n) return;
  float v = src[i];
  float h = bf2f(f2bf_bits(v));
  sto_bf(hi + i, h);
  sto_bf(lo + i, v - h);
}
// nbias[k] = -0.5*||e_k||^2
__global__ __launch_bounds__(256) void nbias_knl(const float* __restrict__ emb, float* __restrict__ nb) {
  int k = blockIdx.x * 256 + threadIdx.x;
  if (k >= 1024) return;
  float s = 0.f;
#pragma unroll
  for (int d = 0; d < 64; ++d) { float e = emb[k * 64 + d]; s = fmaf(e, e, s); }
  nb[k] = -0.5f * s;
}
// per-row argmax of S'[row][0..1024] (== argmin dist), first-index tiebreak; write q + loss
__global__ __launch_bounds__(256) void vq2_knl(const float* __restrict__ S,
                                               const float* __restrict__ zq,
                                               const float* __restrict__ emb,
                                               bf16* __restrict__ q, float* __restrict__ loss) {
  __shared__ float sd[256];
  __shared__ int si[256];
  int row = blockIdx.x;
  int tid = threadIdx.x;
  const float* Sr = S + (long)row * 1024;
  float best = -3.4e38f; int bi = 0;
#pragma unroll
  for (int j = 0; j < 4; ++j) {
    int k = tid + j * 256;
    float v = Sr[k];
    if (v > best) { best = v; bi = k; }   // ascending k: '>' keeps first index
  }
  sd[tid] = best; si[tid] = bi;
  __syncthreads();
  for (int s = 128; s > 0; s >>= 1) {
    if (tid < s) {
      float od = sd[tid + s]; int oi = si[tid + s];
      if (od > sd[tid] || (od == sd[tid] && oi < si[tid])) { sd[tid] = od; si[tid] = oi; }
    }
    __syncthreads();
  }
  int idx = si[0];
  if (tid < 64) {
    float e = emb[(long)idx * 64 + tid];
    float zv = zq[(long)row * 64 + tid];
    float d = e - zv;
    sto_bf(q + (long)row * 64 + tid, e);
    loss[(long)row * 64 + tid] = 1.25f * d * d;
  }
}

// ---------- outc v2: 3x3 conv (64->3)+sigmoid; 1 thread/pixel, 3 ch; scalar weights ----------
__global__ __launch_bounds__(256) void outc_knl(const bf16* __restrict__ in,   // [4][258][258][64]
                                                const float* __restrict__ w,   // [tap][64][3]
                                                const float* __restrict__ bias,
                                                float* __restrict__ out) {     // [4][3][256][256]
  int pix = blockIdx.x * 256 + threadIdx.x;   // 262144 per half
  int x = pix & 255;
  int y = (pix >> 8) & 255;
  int n = pix >> 16;
  float a0 = bias[0], a1 = bias[1], a2 = bias[2];
#pragma unroll
  for (int ky = 0; ky < 3; ++ky) {
#pragma unroll
    for (int kx = 0; kx < 3; ++kx) {
      const bf16* ip = in + (((long)(n * 258 + y + ky)) * 258 + (x + kx)) * 64;
      const int t = ky * 3 + kx;
#pragma unroll
      for (int g = 0; g < 8; ++g) {
        short8 v = *reinterpret_cast<const short8*>(ip + g * 8);
#pragma unroll
        for (int j = 0; j < 8; ++j) {
          float f = bf2f((unsigned short)v[j]);
          int ic = g * 8 + j;
          a0 = fmaf(f, w[(t * 64 + ic) * 3 + 0], a0);   // uniform addr -> s_load
          a1 = fmaf(f, w[(t * 64 + ic) * 3 + 1], a1);
          a2 = fmaf(f, w[(t * 64 + ic) * 3 + 2], a2);
        }
      }
    }
  }
  long ob = ((long)n * 3) * 65536 + ((long)y << 8) + x;
  out[ob]          = 1.f / (1.f + __expf(-a0));
  out[ob + 65536]  = 1.f / (1.f + __expf(-a1));
  out[ob + 131072] = 1.f / (1.f + __expf(-a2));
}

// ---------- host ----------
extern "C" void kernel_launch(void* const* d_in, const int* in_sizes, int n_in,
                              void* d_out, int out_size, void* d_ws, size_t ws_size,
                              hipStream_t stream) {
  (void)in_sizes; (void)n_in; (void)out_size; (void)ws_size;
  const float* x    = (const float*)d_in[0];
  const float* ew1  = (const float*)d_in[1];  const float* eb1 = (const float*)d_in[2];
  const float* ew2  = (const float*)d_in[3];  const float* eb2 = (const float*)d_in[4];
  const float* ew3  = (const float*)d_in[5];  const float* eb3 = (const float*)d_in[6];
  const float* ew4  = (const float*)d_in[7];  const float* eb4 = (const float*)d_in[8];
  const float* pqw  = (const float*)d_in[9];  const float* pqb = (const float*)d_in[10];
  const float* emb  = (const float*)d_in[11];
  const float* poqw = (const float*)d_in[12]; const float* poqb = (const float*)d_in[13];
  const float* dw1  = (const float*)d_in[14]; const float* db1 = (const float*)d_in[15];
  const float* dw2  = (const float*)d_in[16]; const float* db2 = (const float*)d_in[17];
  const float* dw3  = (const float*)d_in[18]; const float* db3 = (const float*)d_in[19];
  const float* dw4  = (const float*)d_in[20]; const float* db4 = (const float*)d_in[21];
  const float* oww  = (const float*)d_in[22]; const float* ob  = (const float*)d_in[23];

  char* wsb = (char*)d_ws;
  size_t off = 0;
  auto alloc = [&](size_t b) -> char* {
    char* p = wsb + off;
    off = (off + b + 255) & ~(size_t)255;
    return p;
  };

  float* w_e1   = (float*)alloc(1728 * 4);
  float* w_ow   = (float*)alloc(1728 * 4);
  float* nbias  = (float*)alloc(1024 * 4);
  bf16* w_eh  = (bf16*)alloc(65536 * 2);   bf16* w_el  = (bf16*)alloc(65536 * 2);
  bf16* w_e2h = (bf16*)alloc(73728 * 2);   bf16* w_e2l = (bf16*)alloc(73728 * 2);
  bf16* w_e3h = (bf16*)alloc(294912 * 2);  bf16* w_e3l = (bf16*)alloc(294912 * 2);
  bf16* w_e4h = (bf16*)alloc(1179648 * 2); bf16* w_e4l = (bf16*)alloc(1179648 * 2);
  bf16* w_pqh = (bf16*)alloc(32768 * 2);   bf16* w_pql = (bf16*)alloc(32768 * 2);
  bf16* w_poq = (bf16*)alloc(32768 * 2);
  bf16* w_d1  = (bf16*)alloc(2359296 * 2);
  bf16* w_d2  = (bf16*)alloc(1179648 * 2);
  bf16* w_d3  = (bf16*)alloc(294912 * 2);
  bf16* w_d4  = (bf16*)alloc(73728 * 2);

  char* RA = alloc(68161536);   // [a1h|a1l] (enc) -> [S|zqh|zql] (VQ) -> u3h (dec)
  char* RB = alloc(68161536);   // enc-half overlay -> decoder arena
  char* RC = alloc(28360704);   // qb | poqO | u1h

  // --- encoder-half overlays ---
  bf16* a1h = (bf16*)RA;                       // 4*258*258*64*2 = 34,080,768
  bf16* a1l = (bf16*)(RA + 34080768);
  // --- VQ overlays in RA (after encoder, before decoder) ---
  float* Sbuf = (float*)RA;                    // 8192*1024*4 = 33,554,432
  bf16* zqh  = (bf16*)(RA + 33554432);         // 8192*64*2 = 1,048,576
  bf16* zql  = (bf16*)(RA + 34603008);
  // --- decoder overlay in RA ---
  bf16* u3h_ = (bf16*)RA;                      // 4*258*258*128*2 = 68,161,536

  bf16* a2h = (bf16*)RB;                       // 4*130*130*128*2 = 17,305,600
  bf16* a2l = (bf16*)(RB + 17305600);
  bf16* a3h = (bf16*)(RB + 34611200);          // 4*66*66*256*2 = 8,921,088
  bf16* a3l = (bf16*)(RB + 43532288);
  bf16* a4h = (bf16*)(RB + 52453376);          // 4*32*32*512*2 = 4,194,304
  bf16* a4l = (bf16*)(RB + 56647680);
  float* zqF = (float*)(RB + 60841984);        // 8192*64*4 = 2,097,152 (full batch)

  // --- decoder overlay in RB (per half) ---
  bf16* u2h_ = (bf16*)RB;                      // 4*130*130*256*2 = 34,611,200
  bf16* c4h_ = (bf16*)RB;                      // 4*258*258*64*2 = 34,080,768
  bf16* c3h_ = (bf16*)(RB + 34611200);         // 4*128*128*128*2 = 16,777,216
  bf16* c2h_ = (bf16*)(RB + 51388416);         // 4*64*64*256*2 = 8,388,608
  bf16* c1h_ = (bf16*)(RB + 59777024);         // 4*32*32*512*2 = 4,194,304 (overlaps zqF; zqF dead by then)

  // --- RC overlays ---
  bf16* qb   = (bf16*)RC;                      // 8192*64*2 = 1,048,576 (full batch)
  bf16* poqO = (bf16*)(RC + 1048576);          // 8*34*34*512*2 = 9,469,952
  bf16* u1h_ = (bf16*)(RC + 10518528);         // 4*66*66*512*2 = 17,842,176

  float* out0 = (float*)d_out;
  float* loss = out0 + 1572864;

  auto G1 = [](long n) { return dim3((unsigned)((n + 255) / 256)); };

  // weight transforms
  wx_tico<<<G1(1728), 256, 0, stream>>>(ew1, w_e1, 64, 3, 9);
  wx_tico<<<G1(1728), 256, 0, stream>>>(oww, w_ow, 3, 64, 9);
  nbias_knl<<<4, 256, 0, stream>>>(emb, nbias);
  wx_toc<<<G1(65536), 256, 0, stream>>>(emb, w_eh, w_el, 1024, 64, 1);   // [k][d] hi/lo
  wx_toc<<<G1(73728), 256, 0, stream>>>(ew2, w_e2h, w_e2l, 128, 64, 9);
  wx_toc<<<G1(294912), 256, 0, stream>>>(ew3, w_e3h, w_e3l, 256, 128, 9);
  wx_toc<<<G1(1179648), 256, 0, stream>>>(ew4, w_e4h, w_e4l, 512, 256, 9);
  wx_toc<<<G1(32768), 256, 0, stream>>>(pqw, w_pqh, w_pql, 64, 512, 1);
  wx_toc<<<G1(32768), 256, 0, stream>>>(poqw, w_poq, (bf16*)nullptr, 512, 64, 1);
  wx_toc<<<G1(2359296), 256, 0, stream>>>(dw1, w_d1, (bf16*)nullptr, 512, 512, 9);
  wx_toc<<<G1(1179648), 256, 0, stream>>>(dw2, w_d2, (bf16*)nullptr, 256, 512, 9);
  wx_toc<<<G1(294912), 256, 0, stream>>>(dw3, w_d3, (bf16*)nullptr, 128, 256, 9);
  wx_toc<<<G1(73728), 256, 0, stream>>>(dw4, w_d4, (bf16*)nullptr, 64, 128, 9);

  auto bz = [&](bf16* p, int N, int Hp, int Wp, int C) {
    long tot = (long)N * (2 * Wp + 2 * Hp - 4) * C;
    bzero_knl<<<G1(tot), 256, 0, stream>>>(p, N, Hp, Wp, C);
  };
  // borders for encoder-half buffers (interiors fully rewritten each half)
  bz(a1h, 4, 258, 258, 64); bz(a1l, 4, 258, 258, 64);
  bz(a2h, 4, 130, 130, 128); bz(a2l, 4, 130, 130, 128);
  bz(a3h, 4, 66, 66, 256);   bz(a3l, 4, 66, 66, 256);

  // ---------- encoder, two batch-halves ----------
  for (int h = 0; h < 2; ++h) {
    const float* xh = x + (size_t)h * 786432;  // 4 images NCHW
    e1_knl<<<16384, 256, 0, stream>>>(xh, w_e1, eb1, a1h, a1l);
    conv_mfma<true, 64, true><<<dim3(1024, 2), 256, 0, stream>>>(
        a1h, a1l, 258, 258, 64, 0, 2, w_e2h, w_e2l, eb2, 128, 128, 128, 2, 1, 130, 130, 1, a2h, a2l);
    conv_mfma<true, 64, true><<<dim3(256, 4), 256, 0, stream>>>(
        a2h, a2l, 130, 130, 128, 1, 2, w_e3h, w_e3l, eb3, 256, 64, 64, 2, 1, 66, 66, 1, a3h, a3l);
    conv_mfma<true, 64, true><<<dim3(64, 8), 256, 0, stream>>>(
        a3h, a3l, 66, 66, 256, 2, 2, w_e4h, w_e4l, eb4, 512, 32, 32, 2, 0, 32, 32, 0, a4h, a4l);
    conv_mfma<true, 64, false><<<dim3(64, 1), 256, 0, stream>>>(
        a4h, a4l, 32, 32, 512, 3, 1, w_pqh, w_pql, pqb, 64, 32, 32, 0, 0, 32, 32, 0,
        zqF + (size_t)h * 262144, nullptr);
  }

  // ---------- VQ: scores via split-bf16 MFMA GEMM, then argmax ----------
  zsplit_knl<<<G1(524288), 256, 0, stream>>>(zqF, zqh, zql, 524288);
  // S'[p][k] = z_p . e_k - ||e_k||^2/2  (M=8192, N=1024, K=64; linear addressing)
  conv_mfma<true, 64, false><<<dim3(128, 16), 256, 0, stream>>>(
      zqh, zql, 32, 32, 64, 0, 1, w_eh, w_el, nbias, 1024, 32, 32, 0, 0, 32, 32, 0, Sbuf, nullptr);
  vq2_knl<<<8192, 256, 0, stream>>>(Sbuf, zqF, emb, qb, loss);

  // post-quant 1x1 (full batch) -> padded 34x34x512
  bz(poqO, 8, 34, 34, 512);
  bz(u1h_, 4, 66, 66, 512);
  conv_mfma<false, 128, false><<<dim3(64, 8), 256, 0, stream>>>(
      qb, nullptr, 32, 32, 64, 0, 1, w_poq, nullptr, poqb, 512, 32, 32, 1, 1, 34, 34, 0, poqO, nullptr);

  // ---------- decoder, two batch-halves ----------
  for (int h = 0; h < 2; ++h) {
    bf16* pin = poqO + (size_t)h * 4 * 34 * 34 * 512;
    float* oout = out0 + (size_t)h * 786432;
    conv_mfma<false, 128, true><<<dim3(32, 8), 256, 0, stream>>>(
        pin, nullptr, 34, 34, 512, 3, 1, w_d1, nullptr, db1, 512, 32, 32, 1, 0, 32, 32, 1, c1h_, nullptr);
    up2_knl<<<G1(4l * 64 * 64 * 128), 256, 0, stream>>>(c1h_, u1h_, 4, 32, 32, 512);
    conv_mfma<false, 128, true><<<dim3(128, 4), 256, 0, stream>>>(
        u1h_, nullptr, 66, 66, 512, 3, 1, w_d2, nullptr, db2, 256, 64, 64, 1, 0, 64, 64, 1, c2h_, nullptr);
    bz(u2h_, 4, 130, 130, 256);
    up2_knl<<<G1(4l * 128 * 128 * 64), 256, 0, stream>>>(c2h_, u2h_, 4, 64, 64, 256);
    conv_mfma<false, 128, true><<<dim3(512, 2), 256, 0, stream>>>(
        u2h_, nullptr, 130, 130, 256, 2, 1, w_d3, nullptr, db3, 128, 128, 128, 1, 0, 128, 128, 1, c3h_, nullptr);
    bz(u3h_, 4, 258, 258, 128);
    up2_knl<<<G1(4l * 256 * 256 * 32), 256, 0, stream>>>(c3h_, u3h_, 4, 128, 128, 128);
    bz(c4h_, 4, 258, 258, 64);
    conv_mfma<false, 128, true><<<dim3(2048, 1), 256, 0, stream>>>(
        u3h_, nullptr, 258, 258, 128, 1, 1, w_d4, nullptr, db4, 64, 256, 256, 1, 1, 258, 258, 0, c4h_, nullptr);
    outc_knl<<<1024, 256, 0, stream>>>(c4h_, w_ow, ob, oout);
  }
}